// Round 1
// baseline (654.676 us; speedup 1.0000x reference)
//
#include <hip/hip_runtime.h>
#include <hip/hip_bf16.h>

// ---------------------------------------------------------------------------
// Problem constants (from reference): N=20000 nodes, D_MODEL=1024, D_FF=286
// (padded to 288 = 9*32 for MFMA), NUM_REL=2, E=320000 edges.
//
// Algorithm restructuring vs reference:
//   norm = rmsnorm(x) -> bf16
//   proj[z] = norm @ W_z   for z in {root, rel0, rel1}   (bf16 MFMA)
//   sums[r][dst] += proj[rel r][src]   (fp32 atomics, D_FF space: 3.6x less
//                                       scatter traffic than D_MODEL space)
//   y2 = elu(proj_root + bias + sum_r sums[r]/max(cnt[r],1)) -> bf16
//   out = hidden + y2 @ wo             (bf16 MFMA + fused residual)
// ---------------------------------------------------------------------------

typedef __bf16  bf16x8  __attribute__((ext_vector_type(8)));
typedef float   floatx4 __attribute__((ext_vector_type(4)));

#define NNODE   20000
#define DMODEL  1024
#define DFF     286
#define DFFP    288     // padded
#define NREL    2

struct alignas(8) bf4 { __bf16 x, y, z, w; };

// ---------------------------------------------------------------------------
// K0: transpose + cast fp32 [K][N] -> bf16 [Nout][Kout], zero-padded.
// ---------------------------------------------------------------------------
__global__ __launch_bounds__(256) void k_transpose_cast(
    const float* __restrict__ src, __bf16* __restrict__ dst,
    int K, int N, int Kout, int Nout)
{
    int id = blockIdx.x * 256 + threadIdx.x;
    if (id >= Kout * Nout) return;
    int n = id / Kout, k = id - n * Kout;
    float v = (n < N && k < K) ? src[(size_t)k * N + n] : 0.0f;
    dst[id] = (__bf16)v;
}

// ---------------------------------------------------------------------------
// K1: T5 RMSNorm, one block (256 thr) per row, float4 loads, bf16 out.
// ---------------------------------------------------------------------------
__global__ __launch_bounds__(256) void k_rmsnorm(
    const float* __restrict__ x, const float* __restrict__ w,
    __bf16* __restrict__ out)
{
    int row = blockIdx.x;
    int t = threadIdx.x;
    float4 v = reinterpret_cast<const float4*>(x + (size_t)row * DMODEL)[t];
    float ss = v.x * v.x + v.y * v.y + v.z * v.z + v.w * v.w;
    #pragma unroll
    for (int off = 32; off; off >>= 1) ss += __shfl_down(ss, off, 64);
    __shared__ float red[4];
    int lane = t & 63, wv = t >> 6;
    if (lane == 0) red[wv] = ss;
    __syncthreads();
    float tot = red[0] + red[1] + red[2] + red[3];
    float scale = rsqrtf(tot * (1.0f / (float)DMODEL) + 1e-6f);
    float4 wv4 = reinterpret_cast<const float4*>(w)[t];
    bf4 o;
    o.x = (__bf16)(v.x * scale * wv4.x);
    o.y = (__bf16)(v.y * scale * wv4.y);
    o.z = (__bf16)(v.z * scale * wv4.z);
    o.w = (__bf16)(v.w * scale * wv4.w);
    reinterpret_cast<bf4*>(out + (size_t)row * DMODEL)[t] = o;
}

// ---------------------------------------------------------------------------
// K2: GEMM1  proj[z] = norm @ B_z    A:[20000][1024] bf16, B^T:[288][1024]
// Tile 128(M) x 96(N) x 32(K); 4 waves 2x2; wave-tile 64x48 = 4x3 MFMAs.
// LDS stride 40 bf16 (80 B) -> 2-way bank aliasing only (free).
// ---------------------------------------------------------------------------
__global__ __launch_bounds__(256) void k_gemm1(
    const __bf16* __restrict__ A, const __bf16* __restrict__ Broot,
    const __bf16* __restrict__ Brel, __bf16* __restrict__ P)
{
    const int mz = blockIdx.z;
    const __bf16* B = (mz == 0) ? Broot : (Brel + (size_t)(mz - 1) * DFFP * DMODEL);
    __bf16* out = P + (size_t)mz * NNODE * DFFP;

    const int m0 = blockIdx.x * 128;
    const int n0 = blockIdx.y * 96;
    const int tid = threadIdx.x;
    const int lane = tid & 63, wave = tid >> 6;
    const int wm = wave >> 1, wn = wave & 1;
    const int quad = lane >> 4, l16 = lane & 15;

    __shared__ __align__(16) __bf16 As[128 * 40];
    __shared__ __align__(16) __bf16 Bs[96 * 40];

    floatx4 zero = {0.f, 0.f, 0.f, 0.f};
    floatx4 acc[4][3];
    #pragma unroll
    for (int i = 0; i < 4; ++i)
        #pragma unroll
        for (int j = 0; j < 3; ++j) acc[i][j] = zero;

    for (int k0 = 0; k0 < DMODEL; k0 += 32) {
        // stage A: 128x32 bf16 = 512 chunks of 8
        #pragma unroll
        for (int i = 0; i < 2; ++i) {
            int chunk = tid + i * 256;
            int row = chunk >> 2, col = (chunk & 3) * 8;
            int grow = m0 + row; if (grow > NNODE - 1) grow = NNODE - 1;
            *reinterpret_cast<uint4*>(&As[row * 40 + col]) =
                *reinterpret_cast<const uint4*>(A + (size_t)grow * DMODEL + k0 + col);
        }
        // stage B: 96x32 = 384 chunks
        {
            int row = tid >> 2, col = (tid & 3) * 8;
            *reinterpret_cast<uint4*>(&Bs[row * 40 + col]) =
                *reinterpret_cast<const uint4*>(B + (size_t)(n0 + row) * DMODEL + k0 + col);
            int chunk = tid + 256;
            if (chunk < 384) {
                row = chunk >> 2; col = (chunk & 3) * 8;
                *reinterpret_cast<uint4*>(&Bs[row * 40 + col]) =
                    *reinterpret_cast<const uint4*>(B + (size_t)(n0 + row) * DMODEL + k0 + col);
            }
        }
        __syncthreads();
        bf16x8 af[4], bq[3];
        #pragma unroll
        for (int i = 0; i < 4; ++i)
            af[i] = *reinterpret_cast<const bf16x8*>(&As[(wm * 64 + i * 16 + l16) * 40 + quad * 8]);
        #pragma unroll
        for (int j = 0; j < 3; ++j)
            bq[j] = *reinterpret_cast<const bf16x8*>(&Bs[(wn * 48 + j * 16 + l16) * 40 + quad * 8]);
        #pragma unroll
        for (int i = 0; i < 4; ++i)
            #pragma unroll
            for (int j = 0; j < 3; ++j)
                acc[i][j] = __builtin_amdgcn_mfma_f32_16x16x32_bf16(af[i], bq[j], acc[i][j], 0, 0, 0);
        __syncthreads();
    }
    // epilogue: C/D layout col = lane&15, row = quad*4 + reg
    #pragma unroll
    for (int i = 0; i < 4; ++i) {
        int rbase = m0 + wm * 64 + i * 16 + quad * 4;
        #pragma unroll
        for (int j = 0; j < 3; ++j) {
            int col = n0 + wn * 48 + j * 16 + l16;
            #pragma unroll
            for (int rr = 0; rr < 4; ++rr) {
                int row = rbase + rr;
                if (row < NNODE) out[(size_t)row * DFFP + col] = (__bf16)acc[i][j][rr];
            }
        }
    }
}

// ---------------------------------------------------------------------------
// K3: edge scatter. One wave per edge; lanes parallel over the 286 features.
//     sums[r][dst][f] += proj_rel[r][src][f];  cnt[r][dst] += 1.
// ---------------------------------------------------------------------------
__global__ __launch_bounds__(256) void k_scatter(
    const int* __restrict__ ei, const int* __restrict__ et,
    const __bf16* __restrict__ proj_rel, float* __restrict__ sums,
    float* __restrict__ cnt, int E)
{
    int gw = blockIdx.x * 4 + (threadIdx.x >> 6);
    int lane = threadIdx.x & 63;
    if (gw >= E) return;
    int src = ei[gw], dst = ei[E + gw], r = et[gw];
    const __bf16* p = proj_rel + ((size_t)r * NNODE + src) * DFFP;
    float* s = sums + ((size_t)r * NNODE + dst) * DFFP;
    if (lane == 0) atomicAdd(&cnt[r * NNODE + dst], 1.0f);
    #pragma unroll
    for (int i = 0; i < 5; ++i) {
        int f = lane + i * 64;
        if (f < DFF) atomicAdd(&s[f], (float)p[f]);
    }
}

// ---------------------------------------------------------------------------
// K4: mean + root + bias, ELU, cast to bf16 (cols 286..287 zero-padded).
// ---------------------------------------------------------------------------
__global__ __launch_bounds__(320) void k_epilogue(
    const __bf16* __restrict__ proj_root, const float* __restrict__ sums,
    const float* __restrict__ cnt, const float* __restrict__ bias,
    __bf16* __restrict__ y2)
{
    int n = blockIdx.x;
    int f = threadIdx.x;
    if (f >= DFFP) return;
    float val = 0.0f;
    if (f < DFF) {
        float ic0 = 1.0f / fmaxf(cnt[n], 1.0f);
        float ic1 = 1.0f / fmaxf(cnt[NNODE + n], 1.0f);
        val = (float)proj_root[(size_t)n * DFFP + f] + bias[f]
            + sums[(size_t)n * DFFP + f] * ic0
            + sums[(size_t)NNODE * DFFP + (size_t)n * DFFP + f] * ic1;
        val = val > 0.0f ? val : (expf(val) - 1.0f);
    }
    y2[(size_t)n * DFFP + f] = (__bf16)val;
}

// ---------------------------------------------------------------------------
// K5: GEMM2  out = hidden + y2 @ wo.  A:[20000][288] bf16, B^T:[1024][288].
// Tile 128x128x32; 4 waves 2x2; wave-tile 64x64 = 4x4 MFMAs. Fused residual.
// ---------------------------------------------------------------------------
__global__ __launch_bounds__(256) void k_gemm2(
    const __bf16* __restrict__ A, const __bf16* __restrict__ Bt,
    const float* __restrict__ hidden, float* __restrict__ out)
{
    const int m0 = blockIdx.x * 128;
    const int n0 = blockIdx.y * 128;
    const int tid = threadIdx.x;
    const int lane = tid & 63, wave = tid >> 6;
    const int wm = wave >> 1, wn = wave & 1;
    const int quad = lane >> 4, l16 = lane & 15;

    __shared__ __align__(16) __bf16 As[128 * 40];
    __shared__ __align__(16) __bf16 Bs[128 * 40];

    floatx4 zero = {0.f, 0.f, 0.f, 0.f};
    floatx4 acc[4][4];
    #pragma unroll
    for (int i = 0; i < 4; ++i)
        #pragma unroll
        for (int j = 0; j < 4; ++j) acc[i][j] = zero;

    for (int k0 = 0; k0 < DFFP; k0 += 32) {
        #pragma unroll
        for (int i = 0; i < 2; ++i) {
            int chunk = tid + i * 256;
            int row = chunk >> 2, col = (chunk & 3) * 8;
            int grow = m0 + row; if (grow > NNODE - 1) grow = NNODE - 1;
            *reinterpret_cast<uint4*>(&As[row * 40 + col]) =
                *reinterpret_cast<const uint4*>(A + (size_t)grow * DFFP + k0 + col);
            *reinterpret_cast<uint4*>(&Bs[row * 40 + col]) =
                *reinterpret_cast<const uint4*>(Bt + (size_t)(n0 + row) * DFFP + k0 + col);
        }
        __syncthreads();
        bf16x8 af[4], bq[4];
        #pragma unroll
        for (int i = 0; i < 4; ++i)
            af[i] = *reinterpret_cast<const bf16x8*>(&As[(wm * 64 + i * 16 + l16) * 40 + quad * 8]);
        #pragma unroll
        for (int j = 0; j < 4; ++j)
            bq[j] = *reinterpret_cast<const bf16x8*>(&Bs[(wn * 64 + j * 16 + l16) * 40 + quad * 8]);
        #pragma unroll
        for (int i = 0; i < 4; ++i)
            #pragma unroll
            for (int j = 0; j < 4; ++j)
                acc[i][j] = __builtin_amdgcn_mfma_f32_16x16x32_bf16(af[i], bq[j], acc[i][j], 0, 0, 0);
        __syncthreads();
    }
    #pragma unroll
    for (int i = 0; i < 4; ++i) {
        int rbase = m0 + wm * 64 + i * 16 + quad * 4;
        #pragma unroll
        for (int j = 0; j < 4; ++j) {
            int col = n0 + wn * 64 + j * 16 + l16;
            #pragma unroll
            for (int rr = 0; rr < 4; ++rr) {
                int row = rbase + rr;
                if (row < NNODE) {
                    size_t idx = (size_t)row * DMODEL + col;
                    out[idx] = hidden[idx] + acc[i][j][rr];
                }
            }
        }
    }
}

// ---------------------------------------------------------------------------
extern "C" void kernel_launch(void* const* d_in, const int* in_sizes, int n_in,
                              void* d_out, int out_size, void* d_ws, size_t ws_size,
                              hipStream_t stream)
{
    const float* hidden   = (const float*)d_in[0];   // [20000][1024]
    const int*   ei       = (const int*)  d_in[1];   // [2][E]
    const int*   et       = (const int*)  d_in[2];   // [E]
    const float* ln_w     = (const float*)d_in[3];   // [1024]
    const float* W_rel    = (const float*)d_in[4];   // [2][1024][286]
    const float* W_root   = (const float*)d_in[5];   // [1024][286]
    const float* bias     = (const float*)d_in[6];   // [286]
    const float* wo       = (const float*)d_in[7];   // [286][1024]
    float* out = (float*)d_out;

    const int E = in_sizes[1] / 2;

    // workspace layout (bytes, all 16B aligned)
    char* ws = (char*)d_ws;
    __bf16* norm_bf   = (__bf16*)(ws + 0);                        // 20000*1024*2 = 40,960,000
    __bf16* proj      = (__bf16*)(ws + 40960000);                 // 3*20000*288*2 = 34,560,000
    float*  sums      = (float*) (ws + 75520000);                 // 2*20000*288*4 = 46,080,000
    float*  cnt       = (float*) (ws + 121600000);                // 2*20000*4 = 160,000
    __bf16* y2        = (__bf16*)(ws + 121760000);                // 20000*288*2 = 11,520,000
    __bf16* wroot_t   = (__bf16*)(ws + 133280000);                // 288*1024*2 = 589,824
    __bf16* wrel_t    = (__bf16*)(ws + 133869824);                // 2*288*1024*2 = 1,179,648
    __bf16* wo_t      = (__bf16*)(ws + 135049472);                // 1024*288*2 = 589,824

    // zero sums + cnt (re-poisoned to 0xAA before every call)
    hipMemsetAsync(sums, 0, 46080000 + 160000, stream);

    // weight transposes (tiny)
    {
        int nblk = (DFFP * DMODEL + 255) / 256;
        k_transpose_cast<<<nblk, 256, 0, stream>>>(W_root, wroot_t, DMODEL, DFF, DMODEL, DFFP);
        k_transpose_cast<<<nblk, 256, 0, stream>>>(W_rel, wrel_t, DMODEL, DFF, DMODEL, DFFP);
        k_transpose_cast<<<nblk, 256, 0, stream>>>(W_rel + (size_t)DMODEL * DFF, wrel_t + (size_t)DFFP * DMODEL,
                                                   DMODEL, DFF, DMODEL, DFFP);
        int nblk2 = (DMODEL * DFFP + 255) / 256;
        k_transpose_cast<<<nblk2, 256, 0, stream>>>(wo, wo_t, DFF, DMODEL, DFFP, DMODEL);
    }

    k_rmsnorm<<<NNODE, 256, 0, stream>>>(hidden, ln_w, norm_bf);

    {
        dim3 grid((NNODE + 127) / 128, DFFP / 96, 3);
        k_gemm1<<<grid, 256, 0, stream>>>(norm_bf, wroot_t, wrel_t, proj);
    }

    k_scatter<<<(E + 3) / 4, 256, 0, stream>>>(ei, et, proj + (size_t)NNODE * DFFP, sums, cnt, E);

    k_epilogue<<<NNODE, 320, 0, stream>>>(proj, sums, cnt, bias, y2);

    {
        dim3 grid((NNODE + 127) / 128, DMODEL / 128);
        k_gemm2<<<grid, 256, 0, stream>>>(y2, wo_t, hidden, out);
    }
}

// Round 2
// 433.045 us; speedup vs baseline: 1.5118x; 1.5118x over previous
//
#include <hip/hip_runtime.h>
#include <hip/hip_bf16.h>

// ---------------------------------------------------------------------------
// N=20000 nodes, D_MODEL=1024, D_FF=286 (pad 288), NUM_REL=2, E=320000.
//
// Pipeline:
//   norm = rmsnorm(x) -> bf16
//   proj[z] = norm @ W_z   z in {root, rel0, rel1}   (bf16 MFMA)
//   counting-sort edges by dst (hist -> scan -> cursor scatter)
//   per-dst wave: gather+sum proj_rel rows, mean+root+bias+ELU -> y2 (bf16)
//   out = hidden + y2 @ wo  (bf16 MFMA + fused residual)
// ---------------------------------------------------------------------------

typedef __bf16  bf16x8  __attribute__((ext_vector_type(8)));
typedef float   floatx4 __attribute__((ext_vector_type(4)));

#define NNODE   20000
#define DMODEL  1024
#define DFF     286
#define DFFP    288
#define NDW     144     // dwords per padded row (288 bf16)
#define NREL    2

struct alignas(8) bf4 { __bf16 x, y, z, w; };

__device__ __forceinline__ float bflo(unsigned u) {
    union { unsigned u; float f; } c; c.u = u << 16; return c.f;
}
__device__ __forceinline__ float bfhi(unsigned u) {
    union { unsigned u; float f; } c; c.u = u & 0xffff0000u; return c.f;
}
__device__ __forceinline__ unsigned packbf(float a, float b) {
    union { __bf16 h[2]; unsigned u; } c;
    c.h[0] = (__bf16)a; c.h[1] = (__bf16)b; return c.u;
}

// ---------------------------------------------------------------------------
// K0: transpose + cast fp32 [K][N] -> bf16 [Nout][Kout], zero-padded.
// ---------------------------------------------------------------------------
__global__ __launch_bounds__(256) void k_transpose_cast(
    const float* __restrict__ src, __bf16* __restrict__ dst,
    int K, int N, int Kout, int Nout)
{
    int id = blockIdx.x * 256 + threadIdx.x;
    if (id >= Kout * Nout) return;
    int n = id / Kout, k = id - n * Kout;
    float v = (n < N && k < K) ? src[(size_t)k * N + n] : 0.0f;
    dst[id] = (__bf16)v;
}

// ---------------------------------------------------------------------------
// K1: T5 RMSNorm, one block (256 thr) per row, float4 loads, bf16 out.
// ---------------------------------------------------------------------------
__global__ __launch_bounds__(256) void k_rmsnorm(
    const float* __restrict__ x, const float* __restrict__ w,
    __bf16* __restrict__ out)
{
    int row = blockIdx.x;
    int t = threadIdx.x;
    float4 v = reinterpret_cast<const float4*>(x + (size_t)row * DMODEL)[t];
    float ss = v.x * v.x + v.y * v.y + v.z * v.z + v.w * v.w;
    #pragma unroll
    for (int off = 32; off; off >>= 1) ss += __shfl_down(ss, off, 64);
    __shared__ float red[4];
    int lane = t & 63, wv = t >> 6;
    if (lane == 0) red[wv] = ss;
    __syncthreads();
    float tot = red[0] + red[1] + red[2] + red[3];
    float scale = rsqrtf(tot * (1.0f / (float)DMODEL) + 1e-6f);
    float4 wv4 = reinterpret_cast<const float4*>(w)[t];
    bf4 o;
    o.x = (__bf16)(v.x * scale * wv4.x);
    o.y = (__bf16)(v.y * scale * wv4.y);
    o.z = (__bf16)(v.z * scale * wv4.z);
    o.w = (__bf16)(v.w * scale * wv4.w);
    reinterpret_cast<bf4*>(out + (size_t)row * DMODEL)[t] = o;
}

// ---------------------------------------------------------------------------
// K2: GEMM1  proj[z] = norm @ B_z    A:[20000][1024] bf16, B^T:[288][1024]
// Tile 128(M) x 96(N) x 32(K); 4 waves 2x2; wave-tile 64x48 = 4x3 MFMAs.
// ---------------------------------------------------------------------------
__global__ __launch_bounds__(256) void k_gemm1(
    const __bf16* __restrict__ A, const __bf16* __restrict__ Broot,
    const __bf16* __restrict__ Brel, __bf16* __restrict__ P)
{
    const int mz = blockIdx.z;
    const __bf16* B = (mz == 0) ? Broot : (Brel + (size_t)(mz - 1) * DFFP * DMODEL);
    __bf16* out = P + (size_t)mz * NNODE * DFFP;

    const int m0 = blockIdx.x * 128;
    const int n0 = blockIdx.y * 96;
    const int tid = threadIdx.x;
    const int lane = tid & 63, wave = tid >> 6;
    const int wm = wave >> 1, wn = wave & 1;
    const int quad = lane >> 4, l16 = lane & 15;

    __shared__ __align__(16) __bf16 As[128 * 40];
    __shared__ __align__(16) __bf16 Bs[96 * 40];

    floatx4 zero = {0.f, 0.f, 0.f, 0.f};
    floatx4 acc[4][3];
    #pragma unroll
    for (int i = 0; i < 4; ++i)
        #pragma unroll
        for (int j = 0; j < 3; ++j) acc[i][j] = zero;

    for (int k0 = 0; k0 < DMODEL; k0 += 32) {
        #pragma unroll
        for (int i = 0; i < 2; ++i) {
            int chunk = tid + i * 256;
            int row = chunk >> 2, col = (chunk & 3) * 8;
            int grow = m0 + row; if (grow > NNODE - 1) grow = NNODE - 1;
            *reinterpret_cast<uint4*>(&As[row * 40 + col]) =
                *reinterpret_cast<const uint4*>(A + (size_t)grow * DMODEL + k0 + col);
        }
        {
            int row = tid >> 2, col = (tid & 3) * 8;
            *reinterpret_cast<uint4*>(&Bs[row * 40 + col]) =
                *reinterpret_cast<const uint4*>(B + (size_t)(n0 + row) * DMODEL + k0 + col);
            int chunk = tid + 256;
            if (chunk < 384) {
                row = chunk >> 2; col = (chunk & 3) * 8;
                *reinterpret_cast<uint4*>(&Bs[row * 40 + col]) =
                    *reinterpret_cast<const uint4*>(B + (size_t)(n0 + row) * DMODEL + k0 + col);
            }
        }
        __syncthreads();
        bf16x8 af[4], bq[3];
        #pragma unroll
        for (int i = 0; i < 4; ++i)
            af[i] = *reinterpret_cast<const bf16x8*>(&As[(wm * 64 + i * 16 + l16) * 40 + quad * 8]);
        #pragma unroll
        for (int j = 0; j < 3; ++j)
            bq[j] = *reinterpret_cast<const bf16x8*>(&Bs[(wn * 48 + j * 16 + l16) * 40 + quad * 8]);
        #pragma unroll
        for (int i = 0; i < 4; ++i)
            #pragma unroll
            for (int j = 0; j < 3; ++j)
                acc[i][j] = __builtin_amdgcn_mfma_f32_16x16x32_bf16(af[i], bq[j], acc[i][j], 0, 0, 0);
        __syncthreads();
    }
    #pragma unroll
    for (int i = 0; i < 4; ++i) {
        int rbase = m0 + wm * 64 + i * 16 + quad * 4;
        #pragma unroll
        for (int j = 0; j < 3; ++j) {
            int col = n0 + wn * 48 + j * 16 + l16;
            #pragma unroll
            for (int rr = 0; rr < 4; ++rr) {
                int row = rbase + rr;
                if (row < NNODE) out[(size_t)row * DFFP + col] = (__bf16)acc[i][j][rr];
            }
        }
    }
}

// ---------------------------------------------------------------------------
// K3a: histogram of edges by dst.
// ---------------------------------------------------------------------------
__global__ __launch_bounds__(256) void k_hist(
    const int* __restrict__ ei, int* __restrict__ bcnt, int E)
{
    int t = blockIdx.x * 256 + threadIdx.x;
    if (t < E) atomicAdd(&bcnt[ei[E + t]], 1);
}

// ---------------------------------------------------------------------------
// K3b: exclusive scan over 20000 bucket counts (single block, 1024 thr).
// Writes boff[0..20000] and a working copy bcur[0..19999].
// ---------------------------------------------------------------------------
__global__ __launch_bounds__(1024) void k_scan(
    const int* __restrict__ bcnt, int* __restrict__ boff, int* __restrict__ bcur)
{
    const int CH = 20;  // 1024*20 = 20480 >= 20000
    __shared__ int s[1024];
    int t = threadIdx.x;
    int base = t * CH;
    int loc[CH];
    int sum = 0;
    #pragma unroll
    for (int i = 0; i < CH; ++i) {
        int idx = base + i;
        int v = (idx < NNODE) ? bcnt[idx] : 0;
        loc[i] = sum; sum += v;
    }
    s[t] = sum;
    __syncthreads();
    for (int off = 1; off < 1024; off <<= 1) {
        int v = (t >= off) ? s[t - off] : 0;
        __syncthreads();
        s[t] += v;
        __syncthreads();
    }
    int prev = (t == 0) ? 0 : s[t - 1];
    #pragma unroll
    for (int i = 0; i < CH; ++i) {
        int idx = base + i;
        if (idx < NNODE) { int o = prev + loc[i]; boff[idx] = o; bcur[idx] = o; }
    }
    if (t == 1023) boff[NNODE] = s[1023];
}

// ---------------------------------------------------------------------------
// K3c: scatter edges into sorted order; payload = src | (r<<20).
// ---------------------------------------------------------------------------
__global__ __launch_bounds__(256) void k_scatter_idx(
    const int* __restrict__ ei, const int* __restrict__ et,
    int* __restrict__ bcur, int* __restrict__ sorted, int E)
{
    int t = blockIdx.x * 256 + threadIdx.x;
    if (t >= E) return;
    int src = ei[t], dst = ei[E + t], r = et[t];
    int pos = atomicAdd(&bcur[dst], 1);
    sorted[pos] = src | (r << 20);
}

// ---------------------------------------------------------------------------
// K4: segment reduce + epilogue. One wave per dst node.
// Lane owns dwords d = lane, lane+64, (lane<16 ? lane+128) of the 144-dword
// feature row. Accumulate per-relation in fp32 regs, then
// y2 = elu(root + bias + sum0/max(c0,1) + sum1/max(c1,1)) -> bf16.
// ---------------------------------------------------------------------------
__global__ __launch_bounds__(256) void k_reduce(
    const int* __restrict__ boff, const int* __restrict__ sorted,
    const __bf16* __restrict__ proj, const float* __restrict__ bias,
    __bf16* __restrict__ y2)
{
    int b = blockIdx.x * 4 + (threadIdx.x >> 6);
    int lane = threadIdx.x & 63;
    int start = boff[b], end = boff[b + 1];

    const unsigned* base1 = reinterpret_cast<const unsigned*>(proj + (size_t)NNODE * DFFP);
    const unsigned* base2 = reinterpret_cast<const unsigned*>(proj + (size_t)2 * NNODE * DFFP);

    float a0[6] = {0.f, 0.f, 0.f, 0.f, 0.f, 0.f};
    float a1[6] = {0.f, 0.f, 0.f, 0.f, 0.f, 0.f};
    int c0 = 0, c1 = 0;
    bool third = (lane < 16);

    for (int e = start; e < end; ++e) {
        int p = sorted[e];
        int src = p & 0xFFFFF;
        int r = p >> 20;
        const unsigned* row = (r ? base2 : base1) + (size_t)src * NDW;
        unsigned d0 = row[lane];
        unsigned d1 = row[lane + 64];
        unsigned d2 = third ? row[lane + 128] : 0u;
        if (r == 0) {
            a0[0] += bflo(d0); a0[1] += bfhi(d0);
            a0[2] += bflo(d1); a0[3] += bfhi(d1);
            a0[4] += bflo(d2); a0[5] += bfhi(d2);
            ++c0;
        } else {
            a1[0] += bflo(d0); a1[1] += bfhi(d0);
            a1[2] += bflo(d1); a1[3] += bfhi(d1);
            a1[4] += bflo(d2); a1[5] += bfhi(d2);
            ++c1;
        }
    }

    float inv0 = 1.0f / fmaxf((float)c0, 1.0f);
    float inv1 = 1.0f / fmaxf((float)c1, 1.0f);

    const unsigned* rootrow = reinterpret_cast<const unsigned*>(proj) + (size_t)b * NDW;
    unsigned* outrow = reinterpret_cast<unsigned*>(y2) + (size_t)b * NDW;

    #pragma unroll
    for (int j = 0; j < 3; ++j) {
        int d = lane + j * 64;
        if (j == 2 && !third) break;
        unsigned rt = rootrow[d];
        int f0 = 2 * d, f1 = 2 * d + 1;
        float bb0 = (f0 < DFF) ? bias[f0] : 0.0f;
        float bb1 = (f1 < DFF) ? bias[f1] : 0.0f;
        float v0 = bflo(rt) + bb0 + a0[2 * j] * inv0 + a1[2 * j] * inv1;
        float v1 = bfhi(rt) + bb1 + a0[2 * j + 1] * inv0 + a1[2 * j + 1] * inv1;
        v0 = v0 > 0.0f ? v0 : (expf(v0) - 1.0f);
        v1 = v1 > 0.0f ? v1 : (expf(v1) - 1.0f);
        outrow[d] = packbf(v0, v1);
    }
}

// ---------------------------------------------------------------------------
// K5: GEMM2  out = hidden + y2 @ wo.  A:[20000][288] bf16, B^T:[1024][288].
// Tile 128x128x32; 4 waves 2x2; wave-tile 64x64 = 4x4 MFMAs. Fused residual.
// ---------------------------------------------------------------------------
__global__ __launch_bounds__(256) void k_gemm2(
    const __bf16* __restrict__ A, const __bf16* __restrict__ Bt,
    const float* __restrict__ hidden, float* __restrict__ out)
{
    const int m0 = blockIdx.x * 128;
    const int n0 = blockIdx.y * 128;
    const int tid = threadIdx.x;
    const int lane = tid & 63, wave = tid >> 6;
    const int wm = wave >> 1, wn = wave & 1;
    const int quad = lane >> 4, l16 = lane & 15;

    __shared__ __align__(16) __bf16 As[128 * 40];
    __shared__ __align__(16) __bf16 Bs[128 * 40];

    floatx4 zero = {0.f, 0.f, 0.f, 0.f};
    floatx4 acc[4][4];
    #pragma unroll
    for (int i = 0; i < 4; ++i)
        #pragma unroll
        for (int j = 0; j < 4; ++j) acc[i][j] = zero;

    for (int k0 = 0; k0 < DFFP; k0 += 32) {
        #pragma unroll
        for (int i = 0; i < 2; ++i) {
            int chunk = tid + i * 256;
            int row = chunk >> 2, col = (chunk & 3) * 8;
            int grow = m0 + row; if (grow > NNODE - 1) grow = NNODE - 1;
            *reinterpret_cast<uint4*>(&As[row * 40 + col]) =
                *reinterpret_cast<const uint4*>(A + (size_t)grow * DFFP + k0 + col);
            *reinterpret_cast<uint4*>(&Bs[row * 40 + col]) =
                *reinterpret_cast<const uint4*>(Bt + (size_t)(n0 + row) * DFFP + k0 + col);
        }
        __syncthreads();
        bf16x8 af[4], bq[4];
        #pragma unroll
        for (int i = 0; i < 4; ++i)
            af[i] = *reinterpret_cast<const bf16x8*>(&As[(wm * 64 + i * 16 + l16) * 40 + quad * 8]);
        #pragma unroll
        for (int j = 0; j < 4; ++j)
            bq[j] = *reinterpret_cast<const bf16x8*>(&Bs[(wn * 64 + j * 16 + l16) * 40 + quad * 8]);
        #pragma unroll
        for (int i = 0; i < 4; ++i)
            #pragma unroll
            for (int j = 0; j < 4; ++j)
                acc[i][j] = __builtin_amdgcn_mfma_f32_16x16x32_bf16(af[i], bq[j], acc[i][j], 0, 0, 0);
        __syncthreads();
    }
    #pragma unroll
    for (int i = 0; i < 4; ++i) {
        int rbase = m0 + wm * 64 + i * 16 + quad * 4;
        #pragma unroll
        for (int j = 0; j < 4; ++j) {
            int col = n0 + wn * 64 + j * 16 + l16;
            #pragma unroll
            for (int rr = 0; rr < 4; ++rr) {
                int row = rbase + rr;
                if (row < NNODE) {
                    size_t idx = (size_t)row * DMODEL + col;
                    out[idx] = hidden[idx] + acc[i][j][rr];
                }
            }
        }
    }
}

// ---------------------------------------------------------------------------
extern "C" void kernel_launch(void* const* d_in, const int* in_sizes, int n_in,
                              void* d_out, int out_size, void* d_ws, size_t ws_size,
                              hipStream_t stream)
{
    const float* hidden   = (const float*)d_in[0];   // [20000][1024]
    const int*   ei       = (const int*)  d_in[1];   // [2][E]
    const int*   et       = (const int*)  d_in[2];   // [E]
    const float* ln_w     = (const float*)d_in[3];   // [1024]
    const float* W_rel    = (const float*)d_in[4];   // [2][1024][286]
    const float* W_root   = (const float*)d_in[5];   // [1024][286]
    const float* bias     = (const float*)d_in[6];   // [286]
    const float* wo       = (const float*)d_in[7];   // [286][1024]
    float* out = (float*)d_out;

    const int E = in_sizes[1] / 2;

    // workspace layout (bytes, 16B aligned)
    char* ws = (char*)d_ws;
    __bf16* norm_bf = (__bf16*)(ws + 0);            // 20000*1024*2 = 40,960,000
    __bf16* proj    = (__bf16*)(ws + 40960000);     // 3*20000*288*2 = 34,560,000
    __bf16* y2      = (__bf16*)(ws + 75520000);     // 20000*288*2 = 11,520,000
    __bf16* wroot_t = (__bf16*)(ws + 87040000);     // 288*1024*2 = 589,824
    __bf16* wrel_t  = (__bf16*)(ws + 87629824);     // 2*288*1024*2 = 1,179,648
    __bf16* wo_t    = (__bf16*)(ws + 88809472);     // 1024*288*2 = 589,824
    int*    bcnt    = (int*)   (ws + 89399296);     // 20000*4 = 80,000
    int*    boff    = (int*)   (ws + 89479296);     // 20001*4 -> pad 80,016
    int*    bcur    = (int*)   (ws + 89559312);     // 20000*4 = 80,000
    int*    sorted  = (int*)   (ws + 89639312);     // 320000*4 = 1,280,000

    hipMemsetAsync(bcnt, 0, 80000, stream);

    {
        int nblk = (DFFP * DMODEL + 255) / 256;
        k_transpose_cast<<<nblk, 256, 0, stream>>>(W_root, wroot_t, DMODEL, DFF, DMODEL, DFFP);
        k_transpose_cast<<<nblk, 256, 0, stream>>>(W_rel, wrel_t, DMODEL, DFF, DMODEL, DFFP);
        k_transpose_cast<<<nblk, 256, 0, stream>>>(W_rel + (size_t)DMODEL * DFF, wrel_t + (size_t)DFFP * DMODEL,
                                                   DMODEL, DFF, DMODEL, DFFP);
        int nblk2 = (DMODEL * DFFP + 255) / 256;
        k_transpose_cast<<<nblk2, 256, 0, stream>>>(wo, wo_t, DFF, DMODEL, DFFP, DMODEL);
    }

    k_rmsnorm<<<NNODE, 256, 0, stream>>>(hidden, ln_w, norm_bf);

    // edge sort (independent of GEMM1)
    k_hist<<<(E + 255) / 256, 256, 0, stream>>>(ei, bcnt, E);
    k_scan<<<1, 1024, 0, stream>>>(bcnt, boff, bcur);
    k_scatter_idx<<<(E + 255) / 256, 256, 0, stream>>>(ei, et, bcur, sorted, E);

    {
        dim3 grid((NNODE + 127) / 128, DFFP / 96, 3);
        k_gemm1<<<grid, 256, 0, stream>>>(norm_bf, wroot_t, wrel_t, proj);
    }

    k_reduce<<<NNODE / 4, 256, 0, stream>>>(boff, sorted, proj, bias, y2);

    {
        dim3 grid((NNODE + 127) / 128, DMODEL / 128);
        k_gemm2<<<grid, 256, 0, stream>>>(y2, wo_t, hidden, out);
    }
}

// Round 3
// 383.779 us; speedup vs baseline: 1.7059x; 1.1284x over previous
//
#include <hip/hip_runtime.h>
#include <hip/hip_bf16.h>

// ---------------------------------------------------------------------------
// N=20000 nodes, D_MODEL=1024, D_FF=286 (pad 288), NUM_REL=2, E=320000.
//
// Pipeline:
//   norm = rmsnorm(x) -> bf16
//   proj[z] = norm @ W_z   z in {root, rel0, rel1}   (bf16 MFMA, z-fastest
//             grid so the 3 blocks sharing an A-tile are L2-coincident)
//   counting-sort edges by dst (hist -> scan -> cursor scatter)
//   per-dst wave: gather+sum proj_rel rows (uint2, unroll 2), mean+root+bias
//                 +ELU -> y2 (bf16)
//   out = hidden + y2 @ wo  (bf16 MFMA + fused residual)
// ---------------------------------------------------------------------------

typedef __bf16  bf16x8  __attribute__((ext_vector_type(8)));
typedef float   floatx4 __attribute__((ext_vector_type(4)));

#define NNODE   20000
#define DMODEL  1024
#define DFF     286
#define DFFP    288
#define NDW     144     // dwords per padded row
#define NPAIR   72      // uint2 per padded row

typedef __attribute__((address_space(1))) const void* gptr_t;
typedef __attribute__((address_space(3))) void*       lptr_t;

struct alignas(8) bf4 { __bf16 x, y, z, w; };

__device__ __forceinline__ float bflo(unsigned u) {
    union { unsigned u; float f; } c; c.u = u << 16; return c.f;
}
__device__ __forceinline__ float bfhi(unsigned u) {
    union { unsigned u; float f; } c; c.u = u & 0xffff0000u; return c.f;
}
__device__ __forceinline__ unsigned packbf(float a, float b) {
    union { __bf16 h[2]; unsigned u; } c;
    c.h[0] = (__bf16)a; c.h[1] = (__bf16)b; return c.u;
}
__device__ __forceinline__ float elu1(float v) {
    return v > 0.0f ? v : (expf(v) - 1.0f);
}

// ---------------------------------------------------------------------------
// K0: tiled transpose + cast fp32 [K][N] -> bf16 [Nout][Kout], zero-padded.
// 32x32 LDS tile; coalesced read and write.
// ---------------------------------------------------------------------------
__global__ __launch_bounds__(256) void k_transpose_cast(
    const float* __restrict__ src, __bf16* __restrict__ dst,
    int K, int N, int Kout, int Nout)
{
    __shared__ float t[32][33];
    int tx = threadIdx.x & 31, ty = threadIdx.x >> 5;
    int k0 = blockIdx.x * 32, n0 = blockIdx.y * 32;
    #pragma unroll
    for (int r = 0; r < 4; ++r) {
        int k = k0 + ty + r * 8, n = n0 + tx;
        t[ty + r * 8][tx] = (k < K && n < N) ? src[(size_t)k * N + n] : 0.0f;
    }
    __syncthreads();
    #pragma unroll
    for (int r = 0; r < 4; ++r) {
        int n = n0 + ty + r * 8, k = k0 + tx;
        if (n < Nout && k < Kout) dst[(size_t)n * Kout + k] = (__bf16)t[tx][ty + r * 8];
    }
}

// ---------------------------------------------------------------------------
// K1: T5 RMSNorm, one block (256 thr) per row, float4 loads, bf16 out.
// ---------------------------------------------------------------------------
__global__ __launch_bounds__(256) void k_rmsnorm(
    const float* __restrict__ x, const float* __restrict__ w,
    __bf16* __restrict__ out)
{
    int row = blockIdx.x;
    int t = threadIdx.x;
    float4 v = reinterpret_cast<const float4*>(x + (size_t)row * DMODEL)[t];
    float ss = v.x * v.x + v.y * v.y + v.z * v.z + v.w * v.w;
    #pragma unroll
    for (int off = 32; off; off >>= 1) ss += __shfl_down(ss, off, 64);
    __shared__ float red[4];
    int lane = t & 63, wv = t >> 6;
    if (lane == 0) red[wv] = ss;
    __syncthreads();
    float tot = red[0] + red[1] + red[2] + red[3];
    float scale = rsqrtf(tot * (1.0f / (float)DMODEL) + 1e-6f);
    float4 wv4 = reinterpret_cast<const float4*>(w)[t];
    bf4 o;
    o.x = (__bf16)(v.x * scale * wv4.x);
    o.y = (__bf16)(v.y * scale * wv4.y);
    o.z = (__bf16)(v.z * scale * wv4.z);
    o.w = (__bf16)(v.w * scale * wv4.w);
    reinterpret_cast<bf4*>(out + (size_t)row * DMODEL)[t] = o;
}

// ---------------------------------------------------------------------------
// K2: GEMM1  proj[z] = norm @ B_z.   A:[20000][1024] bf16, B^T:[288][1024].
// Block = 128(M) x 288(N, full) for one z; 1-D grid, z fastest (A L2 reuse).
// 4 waves 2x2; wave-tile 64x144 = 4x9 MFMAs (16x16x32). BK=32.
// Staging via global_load_lds width=16 into unpadded LDS [row][32].
// 144 acc VGPRs -> __launch_bounds__(256,2).
// ---------------------------------------------------------------------------
__global__ __launch_bounds__(256, 2) void k_gemm1(
    const __bf16* __restrict__ A, const __bf16* __restrict__ Broot,
    const __bf16* __restrict__ Brel, __bf16* __restrict__ P)
{
    const int bid = blockIdx.x;
    const int mt = bid / 3, mz = bid - mt * 3;
    const __bf16* B = (mz == 0) ? Broot : (Brel + (size_t)(mz - 1) * DFFP * DMODEL);
    __bf16* out = P + (size_t)mz * NNODE * DFFP;

    const int m0 = mt * 128;
    const int tid = threadIdx.x;
    const int lane = tid & 63, wave = tid >> 6;
    const int wm = wave >> 1, wn = wave & 1;
    const int quad = lane >> 4, l16 = lane & 15;

    __shared__ __align__(16) __bf16 As[128 * 32];   // 8 KB
    __shared__ __align__(16) __bf16 Bs[288 * 32];   // 18 KB

    floatx4 zero = {0.f, 0.f, 0.f, 0.f};
    floatx4 acc[4][9];
    #pragma unroll
    for (int i = 0; i < 4; ++i)
        #pragma unroll
        for (int j = 0; j < 9; ++j) acc[i][j] = zero;

    // staging lane geometry: each 1KB chunk = 16 rows x 32 bf16
    const int crow = lane >> 2;          // row within chunk
    const int ccol = (lane & 3) * 8;     // bf16 col offset

    for (int k0 = 0; k0 < DMODEL; k0 += 32) {
        // 26 chunks: 8 for A (128 rows), 18 for B (288 rows); wave-strided
        #pragma unroll
        for (int ii = 0; ii < 7; ++ii) {
            int c = wave + ii * 4;
            if (c < 8) {
                int row = c * 16 + crow;
                int grow = m0 + row; if (grow > NNODE - 1) grow = NNODE - 1;
                __builtin_amdgcn_global_load_lds(
                    (gptr_t)(A + (size_t)grow * DMODEL + k0 + ccol),
                    (lptr_t)(As + c * 512), 16, 0, 0);
            } else if (c < 26) {
                int nrow = (c - 8) * 16 + crow;
                __builtin_amdgcn_global_load_lds(
                    (gptr_t)(B + (size_t)nrow * DMODEL + k0 + ccol),
                    (lptr_t)(Bs + (c - 8) * 512), 16, 0, 0);
            }
        }
        __syncthreads();
        bf16x8 af[4], bq[9];
        #pragma unroll
        for (int i = 0; i < 4; ++i)
            af[i] = *reinterpret_cast<const bf16x8*>(As + (wm * 64 + i * 16 + l16) * 32 + quad * 8);
        #pragma unroll
        for (int j = 0; j < 9; ++j)
            bq[j] = *reinterpret_cast<const bf16x8*>(Bs + (wn * 144 + j * 16 + l16) * 32 + quad * 8);
        #pragma unroll
        for (int i = 0; i < 4; ++i)
            #pragma unroll
            for (int j = 0; j < 9; ++j)
                acc[i][j] = __builtin_amdgcn_mfma_f32_16x16x32_bf16(af[i], bq[j], acc[i][j], 0, 0, 0);
        __syncthreads();
    }
    // epilogue: C/D layout col = lane&15, row = quad*4 + reg
    #pragma unroll
    for (int i = 0; i < 4; ++i) {
        int rbase = m0 + wm * 64 + i * 16 + quad * 4;
        #pragma unroll
        for (int j = 0; j < 9; ++j) {
            int col = wn * 144 + j * 16 + l16;
            #pragma unroll
            for (int rr = 0; rr < 4; ++rr) {
                int row = rbase + rr;
                if (row < NNODE) out[(size_t)row * DFFP + col] = (__bf16)acc[i][j][rr];
            }
        }
    }
}

// ---------------------------------------------------------------------------
// K3a: histogram of edges by dst.
// ---------------------------------------------------------------------------
__global__ __launch_bounds__(256) void k_hist(
    const int* __restrict__ ei, int* __restrict__ bcnt, int E)
{
    int t = blockIdx.x * 256 + threadIdx.x;
    if (t < E) atomicAdd(&bcnt[ei[E + t]], 1);
}

// ---------------------------------------------------------------------------
// K3b: exclusive scan over 20000 bucket counts (single block, 1024 thr).
// ---------------------------------------------------------------------------
__global__ __launch_bounds__(1024) void k_scan(
    const int* __restrict__ bcnt, int* __restrict__ boff, int* __restrict__ bcur)
{
    const int CH = 20;
    __shared__ int s[1024];
    int t = threadIdx.x;
    int base = t * CH;
    int loc[CH];
    int sum = 0;
    #pragma unroll
    for (int i = 0; i < CH; ++i) {
        int idx = base + i;
        int v = (idx < NNODE) ? bcnt[idx] : 0;
        loc[i] = sum; sum += v;
    }
    s[t] = sum;
    __syncthreads();
    for (int off = 1; off < 1024; off <<= 1) {
        int v = (t >= off) ? s[t - off] : 0;
        __syncthreads();
        s[t] += v;
        __syncthreads();
    }
    int prev = (t == 0) ? 0 : s[t - 1];
    #pragma unroll
    for (int i = 0; i < CH; ++i) {
        int idx = base + i;
        if (idx < NNODE) { int o = prev + loc[i]; boff[idx] = o; bcur[idx] = o; }
    }
    if (t == 1023) boff[NNODE] = s[1023];
}

// ---------------------------------------------------------------------------
// K3c: scatter edges into sorted order; payload = src | (r<<20).
// ---------------------------------------------------------------------------
__global__ __launch_bounds__(256) void k_scatter_idx(
    const int* __restrict__ ei, const int* __restrict__ et,
    int* __restrict__ bcur, int* __restrict__ sorted, int E)
{
    int t = blockIdx.x * 256 + threadIdx.x;
    if (t >= E) return;
    int src = ei[t], dst = ei[E + t], r = et[t];
    int pos = atomicAdd(&bcur[dst], 1);
    sorted[pos] = src | (r << 20);
}

// ---------------------------------------------------------------------------
// K4: segment reduce + epilogue. One wave per dst node; uint2 gathers
// (lane -> features 4l..4l+3; lanes<8 also own 256+4l..259+4l); edge loop
// unrolled x2 so two rows' loads are in flight.
// ---------------------------------------------------------------------------
__global__ __launch_bounds__(256) void k_reduce(
    const int* __restrict__ boff, const int* __restrict__ sorted,
    const __bf16* __restrict__ proj, const float* __restrict__ bias,
    __bf16* __restrict__ y2)
{
    int b = blockIdx.x * 4 + (threadIdx.x >> 6);
    int lane = threadIdx.x & 63;
    int start = boff[b], end = boff[b + 1];
    bool t8 = lane < 8;

    const uint2* base1 = reinterpret_cast<const uint2*>(proj + (size_t)NNODE * DFFP);
    const uint2* base2 = reinterpret_cast<const uint2*>(proj + (size_t)2 * NNODE * DFFP);

    float a0[4] = {0.f, 0.f, 0.f, 0.f}, a0t[4] = {0.f, 0.f, 0.f, 0.f};
    float a1[4] = {0.f, 0.f, 0.f, 0.f}, a1t[4] = {0.f, 0.f, 0.f, 0.f};
    int c0 = 0, c1 = 0;
    uint2 zz; zz.x = 0u; zz.y = 0u;

    int e = start;
    for (; e + 2 <= end; e += 2) {
        int p0 = sorted[e], p1 = sorted[e + 1];
        int r0i = p0 >> 20, r1i = p1 >> 20;
        const uint2* r0 = (r0i ? base2 : base1) + (size_t)(p0 & 0xFFFFF) * NPAIR;
        const uint2* r1 = (r1i ? base2 : base1) + (size_t)(p1 & 0xFFFFF) * NPAIR;
        uint2 x0 = r0[lane];
        uint2 x1 = r1[lane];
        uint2 y0 = t8 ? r0[64 + lane] : zz;
        uint2 y1 = t8 ? r1[64 + lane] : zz;
        if (r0i) {
            a1[0] += bflo(x0.x); a1[1] += bfhi(x0.x); a1[2] += bflo(x0.y); a1[3] += bfhi(x0.y);
            a1t[0] += bflo(y0.x); a1t[1] += bfhi(y0.x); a1t[2] += bflo(y0.y); a1t[3] += bfhi(y0.y);
            ++c1;
        } else {
            a0[0] += bflo(x0.x); a0[1] += bfhi(x0.x); a0[2] += bflo(x0.y); a0[3] += bfhi(x0.y);
            a0t[0] += bflo(y0.x); a0t[1] += bfhi(y0.x); a0t[2] += bflo(y0.y); a0t[3] += bfhi(y0.y);
            ++c0;
        }
        if (r1i) {
            a1[0] += bflo(x1.x); a1[1] += bfhi(x1.x); a1[2] += bflo(x1.y); a1[3] += bfhi(x1.y);
            a1t[0] += bflo(y1.x); a1t[1] += bfhi(y1.x); a1t[2] += bflo(y1.y); a1t[3] += bfhi(y1.y);
            ++c1;
        } else {
            a0[0] += bflo(x1.x); a0[1] += bfhi(x1.x); a0[2] += bflo(x1.y); a0[3] += bfhi(x1.y);
            a0t[0] += bflo(y1.x); a0t[1] += bfhi(y1.x); a0t[2] += bflo(y1.y); a0t[3] += bfhi(y1.y);
            ++c0;
        }
    }
    if (e < end) {
        int p0 = sorted[e];
        int r0i = p0 >> 20;
        const uint2* r0 = (r0i ? base2 : base1) + (size_t)(p0 & 0xFFFFF) * NPAIR;
        uint2 x0 = r0[lane];
        uint2 y0 = t8 ? r0[64 + lane] : zz;
        if (r0i) {
            a1[0] += bflo(x0.x); a1[1] += bfhi(x0.x); a1[2] += bflo(x0.y); a1[3] += bfhi(x0.y);
            a1t[0] += bflo(y0.x); a1t[1] += bfhi(y0.x); a1t[2] += bflo(y0.y); a1t[3] += bfhi(y0.y);
            ++c1;
        } else {
            a0[0] += bflo(x0.x); a0[1] += bfhi(x0.x); a0[2] += bflo(x0.y); a0[3] += bfhi(x0.y);
            a0t[0] += bflo(y0.x); a0t[1] += bfhi(y0.x); a0t[2] += bflo(y0.y); a0t[3] += bfhi(y0.y);
            ++c0;
        }
    }

    float inv0 = 1.0f / fmaxf((float)c0, 1.0f);
    float inv1 = 1.0f / fmaxf((float)c1, 1.0f);

    const uint2* rootrow = reinterpret_cast<const uint2*>(proj) + (size_t)b * NPAIR;
    uint2* outrow = reinterpret_cast<uint2*>(y2) + (size_t)b * NPAIR;

    {
        uint2 rt = rootrow[lane];
        int f = 4 * lane;                 // max 255 < 286: no guard
        float v0 = bflo(rt.x) + bias[f]     + a0[0] * inv0 + a1[0] * inv1;
        float v1 = bfhi(rt.x) + bias[f + 1] + a0[1] * inv0 + a1[1] * inv1;
        float v2 = bflo(rt.y) + bias[f + 2] + a0[2] * inv0 + a1[2] * inv1;
        float v3 = bfhi(rt.y) + bias[f + 3] + a0[3] * inv0 + a1[3] * inv1;
        uint2 o; o.x = packbf(elu1(v0), elu1(v1)); o.y = packbf(elu1(v2), elu1(v3));
        outrow[lane] = o;
    }
    if (t8) {
        uint2 rt = rootrow[64 + lane];
        int f = 256 + 4 * lane;           // 256..287: guard vs 286
        float b0 = (f     < DFF) ? bias[f]     : 0.0f;
        float b1 = (f + 1 < DFF) ? bias[f + 1] : 0.0f;
        float b2 = (f + 2 < DFF) ? bias[f + 2] : 0.0f;
        float b3 = (f + 3 < DFF) ? bias[f + 3] : 0.0f;
        float v0 = bflo(rt.x) + b0 + a0t[0] * inv0 + a1t[0] * inv1;
        float v1 = bfhi(rt.x) + b1 + a0t[1] * inv0 + a1t[1] * inv1;
        float v2 = bflo(rt.y) + b2 + a0t[2] * inv0 + a1t[2] * inv1;
        float v3 = bfhi(rt.y) + b3 + a0t[3] * inv0 + a1t[3] * inv1;
        uint2 o; o.x = packbf(elu1(v0), elu1(v1)); o.y = packbf(elu1(v2), elu1(v3));
        outrow[64 + lane] = o;
    }
}

// ---------------------------------------------------------------------------
// K5: GEMM2  out = hidden + y2 @ wo.  A:[20000][288] bf16, B^T:[1024][288].
// Tile 128x128x32; 4 waves 2x2; wave-tile 64x64 = 4x4 MFMAs. Fused residual.
// ---------------------------------------------------------------------------
__global__ __launch_bounds__(256) void k_gemm2(
    const __bf16* __restrict__ A, const __bf16* __restrict__ Bt,
    const float* __restrict__ hidden, float* __restrict__ out)
{
    const int m0 = blockIdx.x * 128;
    const int n0 = blockIdx.y * 128;
    const int tid = threadIdx.x;
    const int lane = tid & 63, wave = tid >> 6;
    const int wm = wave >> 1, wn = wave & 1;
    const int quad = lane >> 4, l16 = lane & 15;

    __shared__ __align__(16) __bf16 As[128 * 40];
    __shared__ __align__(16) __bf16 Bs[128 * 40];

    floatx4 zero = {0.f, 0.f, 0.f, 0.f};
    floatx4 acc[4][4];
    #pragma unroll
    for (int i = 0; i < 4; ++i)
        #pragma unroll
        for (int j = 0; j < 4; ++j) acc[i][j] = zero;

    for (int k0 = 0; k0 < DFFP; k0 += 32) {
        #pragma unroll
        for (int i = 0; i < 2; ++i) {
            int chunk = tid + i * 256;
            int row = chunk >> 2, col = (chunk & 3) * 8;
            int grow = m0 + row; if (grow > NNODE - 1) grow = NNODE - 1;
            *reinterpret_cast<uint4*>(&As[row * 40 + col]) =
                *reinterpret_cast<const uint4*>(A + (size_t)grow * DFFP + k0 + col);
            *reinterpret_cast<uint4*>(&Bs[row * 40 + col]) =
                *reinterpret_cast<const uint4*>(Bt + (size_t)(n0 + row) * DFFP + k0 + col);
        }
        __syncthreads();
        bf16x8 af[4], bq[4];
        #pragma unroll
        for (int i = 0; i < 4; ++i)
            af[i] = *reinterpret_cast<const bf16x8*>(&As[(wm * 64 + i * 16 + l16) * 40 + quad * 8]);
        #pragma unroll
        for (int j = 0; j < 4; ++j)
            bq[j] = *reinterpret_cast<const bf16x8*>(&Bs[(wn * 64 + j * 16 + l16) * 40 + quad * 8]);
        #pragma unroll
        for (int i = 0; i < 4; ++i)
            #pragma unroll
            for (int j = 0; j < 4; ++j)
                acc[i][j] = __builtin_amdgcn_mfma_f32_16x16x32_bf16(af[i], bq[j], acc[i][j], 0, 0, 0);
        __syncthreads();
    }
    #pragma unroll
    for (int i = 0; i < 4; ++i) {
        int rbase = m0 + wm * 64 + i * 16 + quad * 4;
        #pragma unroll
        for (int j = 0; j < 4; ++j) {
            int col = n0 + wn * 64 + j * 16 + l16;
            #pragma unroll
            for (int rr = 0; rr < 4; ++rr) {
                int row = rbase + rr;
                if (row < NNODE) {
                    size_t idx = (size_t)row * DMODEL + col;
                    out[idx] = hidden[idx] + acc[i][j][rr];
                }
            }
        }
    }
}

// ---------------------------------------------------------------------------
extern "C" void kernel_launch(void* const* d_in, const int* in_sizes, int n_in,
                              void* d_out, int out_size, void* d_ws, size_t ws_size,
                              hipStream_t stream)
{
    const float* hidden   = (const float*)d_in[0];   // [20000][1024]
    const int*   ei       = (const int*)  d_in[1];   // [2][E]
    const int*   et       = (const int*)  d_in[2];   // [E]
    const float* ln_w     = (const float*)d_in[3];   // [1024]
    const float* W_rel    = (const float*)d_in[4];   // [2][1024][286]
    const float* W_root   = (const float*)d_in[5];   // [1024][286]
    const float* bias     = (const float*)d_in[6];   // [286]
    const float* wo       = (const float*)d_in[7];   // [286][1024]
    float* out = (float*)d_out;

    const int E = in_sizes[1] / 2;

    // workspace layout (bytes, 16B aligned)
    char* ws = (char*)d_ws;
    __bf16* norm_bf = (__bf16*)(ws + 0);            // 40,960,000
    __bf16* proj    = (__bf16*)(ws + 40960000);     // 34,560,000
    __bf16* y2      = (__bf16*)(ws + 75520000);     // 11,520,000
    __bf16* wroot_t = (__bf16*)(ws + 87040000);     // 589,824
    __bf16* wrel_t  = (__bf16*)(ws + 87629824);     // 1,179,648
    __bf16* wo_t    = (__bf16*)(ws + 88809472);     // 589,824
    int*    bcnt    = (int*)   (ws + 89399296);     // 80,000
    int*    boff    = (int*)   (ws + 89479296);     // 80,016
    int*    bcur    = (int*)   (ws + 89559312);     // 80,000
    int*    sorted  = (int*)   (ws + 89639312);     // 1,280,000

    hipMemsetAsync(bcnt, 0, 80000, stream);

    {
        dim3 g1((DMODEL + 31) / 32, (DFFP + 31) / 32);   // (32, 9)
        k_transpose_cast<<<g1, 256, 0, stream>>>(W_root, wroot_t, DMODEL, DFF, DMODEL, DFFP);
        k_transpose_cast<<<g1, 256, 0, stream>>>(W_rel, wrel_t, DMODEL, DFF, DMODEL, DFFP);
        k_transpose_cast<<<g1, 256, 0, stream>>>(W_rel + (size_t)DMODEL * DFF,
                                                 wrel_t + (size_t)DFFP * DMODEL,
                                                 DMODEL, DFF, DMODEL, DFFP);
        dim3 g2((DFFP + 31) / 32, (DMODEL + 31) / 32);   // (9, 32)
        k_transpose_cast<<<g2, 256, 0, stream>>>(wo, wo_t, DFF, DMODEL, DFFP, DMODEL);
    }

    k_rmsnorm<<<NNODE, 256, 0, stream>>>(hidden, ln_w, norm_bf);

    // edge sort
    k_hist<<<(E + 255) / 256, 256, 0, stream>>>(ei, bcnt, E);
    k_scan<<<1, 1024, 0, stream>>>(bcnt, boff, bcur);
    k_scatter_idx<<<(E + 255) / 256, 256, 0, stream>>>(ei, et, bcur, sorted, E);

    {
        int nmt = (NNODE + 127) / 128;   // 157
        k_gemm1<<<nmt * 3, 256, 0, stream>>>(norm_bf, wroot_t, wrel_t, proj);
    }

    k_reduce<<<NNODE / 4, 256, 0, stream>>>(boff, sorted, proj, bias, y2);

    {
        dim3 grid((NNODE + 127) / 128, DMODEL / 128);
        k_gemm2<<<grid, 256, 0, stream>>>(y2, wo_t, hidden, out);
    }
}

// Round 4
// 382.680 us; speedup vs baseline: 1.7108x; 1.0029x over previous
//
#include <hip/hip_runtime.h>
#include <hip/hip_bf16.h>

// ---------------------------------------------------------------------------
// N=20000 nodes, D_MODEL=1024, D_FF=286 (pad 288), NUM_REL=2, E=320000.
//
// Pipeline:
//   norm = rmsnorm(x) -> bf16
//   proj[z] = norm @ W_z   z in {root, rel0, rel1}   (bf16 MFMA, z-fastest)
//   counting-sort edges by dst (hist -> scan -> cursor scatter)
//   per-dst wave: gather+sum proj_rel rows (unroll 4, branchless), mean+root
//                 +bias+ELU -> y2 (bf16)
//   out = hidden + y2 @ wo  (bf16 MFMA, hidden reg-prefetch, dbuf staging)
// ---------------------------------------------------------------------------

typedef __bf16  bf16x8  __attribute__((ext_vector_type(8)));
typedef float   floatx4 __attribute__((ext_vector_type(4)));

#define NNODE   20000
#define DMODEL  1024
#define DFF     286
#define DFFP    288
#define NDW     144     // dwords per padded row
#define NPAIR   72      // uint2 per padded row

typedef __attribute__((address_space(1))) const void* gptr_t;
typedef __attribute__((address_space(3))) void*       lptr_t;

struct alignas(8) bf4 { __bf16 x, y, z, w; };

__device__ __forceinline__ float bflo(unsigned u) {
    union { unsigned u; float f; } c; c.u = u << 16; return c.f;
}
__device__ __forceinline__ float bfhi(unsigned u) {
    union { unsigned u; float f; } c; c.u = u & 0xffff0000u; return c.f;
}
__device__ __forceinline__ unsigned packbf(float a, float b) {
    union { __bf16 h[2]; unsigned u; } c;
    c.h[0] = (__bf16)a; c.h[1] = (__bf16)b; return c.u;
}
__device__ __forceinline__ float elu1(float v) {
    return v > 0.0f ? v : (expf(v) - 1.0f);
}

// ---------------------------------------------------------------------------
// K0: tiled transpose + cast fp32 [K][N] -> bf16 [Nout][Kout], zero-padded.
// ---------------------------------------------------------------------------
__global__ __launch_bounds__(256) void k_transpose_cast(
    const float* __restrict__ src, __bf16* __restrict__ dst,
    int K, int N, int Kout, int Nout)
{
    __shared__ float t[32][33];
    int tx = threadIdx.x & 31, ty = threadIdx.x >> 5;
    int k0 = blockIdx.x * 32, n0 = blockIdx.y * 32;
    #pragma unroll
    for (int r = 0; r < 4; ++r) {
        int k = k0 + ty + r * 8, n = n0 + tx;
        t[ty + r * 8][tx] = (k < K && n < N) ? src[(size_t)k * N + n] : 0.0f;
    }
    __syncthreads();
    #pragma unroll
    for (int r = 0; r < 4; ++r) {
        int n = n0 + ty + r * 8, k = k0 + tx;
        if (n < Nout && k < Kout) dst[(size_t)n * Kout + k] = (__bf16)t[tx][ty + r * 8];
    }
}

// ---------------------------------------------------------------------------
// K1: T5 RMSNorm, one block (256 thr) per row, float4 loads, bf16 out.
// ---------------------------------------------------------------------------
__global__ __launch_bounds__(256) void k_rmsnorm(
    const float* __restrict__ x, const float* __restrict__ w,
    __bf16* __restrict__ out)
{
    int row = blockIdx.x;
    int t = threadIdx.x;
    float4 v = reinterpret_cast<const float4*>(x + (size_t)row * DMODEL)[t];
    float ss = v.x * v.x + v.y * v.y + v.z * v.z + v.w * v.w;
    #pragma unroll
    for (int off = 32; off; off >>= 1) ss += __shfl_down(ss, off, 64);
    __shared__ float red[4];
    int lane = t & 63, wv = t >> 6;
    if (lane == 0) red[wv] = ss;
    __syncthreads();
    float tot = red[0] + red[1] + red[2] + red[3];
    float scale = rsqrtf(tot * (1.0f / (float)DMODEL) + 1e-6f);
    float4 wv4 = reinterpret_cast<const float4*>(w)[t];
    bf4 o;
    o.x = (__bf16)(v.x * scale * wv4.x);
    o.y = (__bf16)(v.y * scale * wv4.y);
    o.z = (__bf16)(v.z * scale * wv4.z);
    o.w = (__bf16)(v.w * scale * wv4.w);
    reinterpret_cast<bf4*>(out + (size_t)row * DMODEL)[t] = o;
}

// ---------------------------------------------------------------------------
// K2: GEMM1  proj[z] = norm @ B_z.   A:[20000][1024] bf16, B^T:[288][1024].
// Block = 128(M) x 288(N) for one z; 1-D grid, z fastest (A L2 reuse).
// 4 waves 2x2; wave-tile 64x144 = 4x9 MFMAs. global_load_lds staging.
// ---------------------------------------------------------------------------
__global__ __launch_bounds__(256, 2) void k_gemm1(
    const __bf16* __restrict__ A, const __bf16* __restrict__ Broot,
    const __bf16* __restrict__ Brel, __bf16* __restrict__ P)
{
    const int bid = blockIdx.x;
    const int mt = bid / 3, mz = bid - mt * 3;
    const __bf16* B = (mz == 0) ? Broot : (Brel + (size_t)(mz - 1) * DFFP * DMODEL);
    __bf16* out = P + (size_t)mz * NNODE * DFFP;

    const int m0 = mt * 128;
    const int tid = threadIdx.x;
    const int lane = tid & 63, wave = tid >> 6;
    const int wm = wave >> 1, wn = wave & 1;
    const int quad = lane >> 4, l16 = lane & 15;

    __shared__ __align__(16) __bf16 As[128 * 32];   // 8 KB
    __shared__ __align__(16) __bf16 Bs[288 * 32];   // 18 KB

    floatx4 zero = {0.f, 0.f, 0.f, 0.f};
    floatx4 acc[4][9];
    #pragma unroll
    for (int i = 0; i < 4; ++i)
        #pragma unroll
        for (int j = 0; j < 9; ++j) acc[i][j] = zero;

    const int crow = lane >> 2;          // row within 16-row chunk
    const int ccol = (lane & 3) * 8;     // bf16 col offset

    for (int k0 = 0; k0 < DMODEL; k0 += 32) {
        #pragma unroll
        for (int ii = 0; ii < 7; ++ii) {
            int c = wave + ii * 4;
            if (c < 8) {
                int row = c * 16 + crow;
                int grow = m0 + row; if (grow > NNODE - 1) grow = NNODE - 1;
                __builtin_amdgcn_global_load_lds(
                    (gptr_t)(A + (size_t)grow * DMODEL + k0 + ccol),
                    (lptr_t)(As + c * 512), 16, 0, 0);
            } else if (c < 26) {
                int nrow = (c - 8) * 16 + crow;
                __builtin_amdgcn_global_load_lds(
                    (gptr_t)(B + (size_t)nrow * DMODEL + k0 + ccol),
                    (lptr_t)(Bs + (c - 8) * 512), 16, 0, 0);
            }
        }
        __syncthreads();
        bf16x8 af[4], bq[9];
        #pragma unroll
        for (int i = 0; i < 4; ++i)
            af[i] = *reinterpret_cast<const bf16x8*>(As + (wm * 64 + i * 16 + l16) * 32 + quad * 8);
        #pragma unroll
        for (int j = 0; j < 9; ++j)
            bq[j] = *reinterpret_cast<const bf16x8*>(Bs + (wn * 144 + j * 16 + l16) * 32 + quad * 8);
        #pragma unroll
        for (int i = 0; i < 4; ++i)
            #pragma unroll
            for (int j = 0; j < 9; ++j)
                acc[i][j] = __builtin_amdgcn_mfma_f32_16x16x32_bf16(af[i], bq[j], acc[i][j], 0, 0, 0);
        __syncthreads();
    }
    #pragma unroll
    for (int i = 0; i < 4; ++i) {
        int rbase = m0 + wm * 64 + i * 16 + quad * 4;
        #pragma unroll
        for (int j = 0; j < 9; ++j) {
            int col = wn * 144 + j * 16 + l16;
            #pragma unroll
            for (int rr = 0; rr < 4; ++rr) {
                int row = rbase + rr;
                if (row < NNODE) out[(size_t)row * DFFP + col] = (__bf16)acc[i][j][rr];
            }
        }
    }
}

// ---------------------------------------------------------------------------
// K3a: histogram of edges by dst.
// ---------------------------------------------------------------------------
__global__ __launch_bounds__(256) void k_hist(
    const int* __restrict__ ei, int* __restrict__ bcnt, int E)
{
    int t = blockIdx.x * 256 + threadIdx.x;
    if (t < E) atomicAdd(&bcnt[ei[E + t]], 1);
}

// ---------------------------------------------------------------------------
// K3b: exclusive scan over 20000 bucket counts (single block, 1024 thr).
// ---------------------------------------------------------------------------
__global__ __launch_bounds__(1024) void k_scan(
    const int* __restrict__ bcnt, int* __restrict__ boff, int* __restrict__ bcur)
{
    const int CH = 20;
    __shared__ int s[1024];
    int t = threadIdx.x;
    int base = t * CH;
    int loc[CH];
    int sum = 0;
    #pragma unroll
    for (int i = 0; i < CH; ++i) {
        int idx = base + i;
        int v = (idx < NNODE) ? bcnt[idx] : 0;
        loc[i] = sum; sum += v;
    }
    s[t] = sum;
    __syncthreads();
    for (int off = 1; off < 1024; off <<= 1) {
        int v = (t >= off) ? s[t - off] : 0;
        __syncthreads();
        s[t] += v;
        __syncthreads();
    }
    int prev = (t == 0) ? 0 : s[t - 1];
    #pragma unroll
    for (int i = 0; i < CH; ++i) {
        int idx = base + i;
        if (idx < NNODE) { int o = prev + loc[i]; boff[idx] = o; bcur[idx] = o; }
    }
    if (t == 1023) boff[NNODE] = s[1023];
}

// ---------------------------------------------------------------------------
// K3c: scatter edges into sorted order; payload = src | (r<<20).
// ---------------------------------------------------------------------------
__global__ __launch_bounds__(256) void k_scatter_idx(
    const int* __restrict__ ei, const int* __restrict__ et,
    int* __restrict__ bcur, int* __restrict__ sorted, int E)
{
    int t = blockIdx.x * 256 + threadIdx.x;
    if (t >= E) return;
    int src = ei[t], dst = ei[E + t], r = et[t];
    int pos = atomicAdd(&bcur[dst], 1);
    sorted[pos] = src | (r << 20);
}

// ---------------------------------------------------------------------------
// K4: segment reduce + epilogue. One wave per dst node; uint2 gathers,
// edge loop unrolled x4 (8 gathers in flight), branchless accumulate via
// per-relation weight FMAs.
// ---------------------------------------------------------------------------
__global__ __launch_bounds__(256) void k_reduce(
    const int* __restrict__ boff, const int* __restrict__ sorted,
    const __bf16* __restrict__ proj, const float* __restrict__ bias,
    __bf16* __restrict__ y2)
{
    int b = blockIdx.x * 4 + (threadIdx.x >> 6);
    int lane = threadIdx.x & 63;
    int start = boff[b], end = boff[b + 1];
    bool t8 = lane < 8;

    const uint2* base1 = reinterpret_cast<const uint2*>(proj + (size_t)NNODE * DFFP);
    const size_t relstride = (size_t)NNODE * NPAIR;

    float a0[4] = {0.f, 0.f, 0.f, 0.f}, b0a[4] = {0.f, 0.f, 0.f, 0.f};
    float a1[4] = {0.f, 0.f, 0.f, 0.f}, b1a[4] = {0.f, 0.f, 0.f, 0.f};
    float c0 = 0.f, c1 = 0.f;
    uint2 zz; zz.x = 0u; zz.y = 0u;

    int e = start;
    for (; e + 4 <= end; e += 4) {
        uint2 x[4], y[4]; float w1[4];
        #pragma unroll
        for (int u = 0; u < 4; ++u) {
            int p = sorted[e + u];
            int ri = p >> 20;
            w1[u] = (float)ri;
            const uint2* row = base1 + (size_t)(p & 0xFFFFF) * NPAIR + (ri ? relstride : 0);
            x[u] = row[lane];
            y[u] = t8 ? row[64 + lane] : zz;
        }
        #pragma unroll
        for (int u = 0; u < 4; ++u) {
            float W1 = w1[u], W0 = 1.0f - W1;
            c0 += W0; c1 += W1;
            float v0 = bflo(x[u].x), v1 = bfhi(x[u].x), v2 = bflo(x[u].y), v3 = bfhi(x[u].y);
            a0[0] += W0 * v0; a1[0] += W1 * v0;
            a0[1] += W0 * v1; a1[1] += W1 * v1;
            a0[2] += W0 * v2; a1[2] += W1 * v2;
            a0[3] += W0 * v3; a1[3] += W1 * v3;
            float u0 = bflo(y[u].x), u1 = bfhi(y[u].x), u2 = bflo(y[u].y), u3 = bfhi(y[u].y);
            b0a[0] += W0 * u0; b1a[0] += W1 * u0;
            b0a[1] += W0 * u1; b1a[1] += W1 * u1;
            b0a[2] += W0 * u2; b1a[2] += W1 * u2;
            b0a[3] += W0 * u3; b1a[3] += W1 * u3;
        }
    }
    for (; e < end; ++e) {
        int p = sorted[e];
        int ri = p >> 20;
        float W1 = (float)ri, W0 = 1.0f - W1;
        const uint2* row = base1 + (size_t)(p & 0xFFFFF) * NPAIR + (ri ? relstride : 0);
        uint2 x = row[lane];
        uint2 y = t8 ? row[64 + lane] : zz;
        c0 += W0; c1 += W1;
        float v0 = bflo(x.x), v1 = bfhi(x.x), v2 = bflo(x.y), v3 = bfhi(x.y);
        a0[0] += W0 * v0; a1[0] += W1 * v0;
        a0[1] += W0 * v1; a1[1] += W1 * v1;
        a0[2] += W0 * v2; a1[2] += W1 * v2;
        a0[3] += W0 * v3; a1[3] += W1 * v3;
        float u0 = bflo(y.x), u1 = bfhi(y.x), u2 = bflo(y.y), u3 = bfhi(y.y);
        b0a[0] += W0 * u0; b1a[0] += W1 * u0;
        b0a[1] += W0 * u1; b1a[1] += W1 * u1;
        b0a[2] += W0 * u2; b1a[2] += W1 * u2;
        b0a[3] += W0 * u3; b1a[3] += W1 * u3;
    }

    float inv0 = 1.0f / fmaxf(c0, 1.0f);
    float inv1 = 1.0f / fmaxf(c1, 1.0f);

    const uint2* rootrow = reinterpret_cast<const uint2*>(proj) + (size_t)b * NPAIR;
    uint2* outrow = reinterpret_cast<uint2*>(y2) + (size_t)b * NPAIR;

    {
        uint2 rt = rootrow[lane];
        int f = 4 * lane;                 // max 255 < 286: no guard
        float v0 = bflo(rt.x) + bias[f]     + a0[0] * inv0 + a1[0] * inv1;
        float v1 = bfhi(rt.x) + bias[f + 1] + a0[1] * inv0 + a1[1] * inv1;
        float v2 = bflo(rt.y) + bias[f + 2] + a0[2] * inv0 + a1[2] * inv1;
        float v3 = bfhi(rt.y) + bias[f + 3] + a0[3] * inv0 + a1[3] * inv1;
        uint2 o; o.x = packbf(elu1(v0), elu1(v1)); o.y = packbf(elu1(v2), elu1(v3));
        outrow[lane] = o;
    }
    if (t8) {
        uint2 rt = rootrow[64 + lane];
        int f = 256 + 4 * lane;           // 256..287: guard vs 286
        float g0 = (f     < DFF) ? bias[f]     : 0.0f;
        float g1 = (f + 1 < DFF) ? bias[f + 1] : 0.0f;
        float g2 = (f + 2 < DFF) ? bias[f + 2] : 0.0f;
        float g3 = (f + 3 < DFF) ? bias[f + 3] : 0.0f;
        float v0 = bflo(rt.x) + g0 + b0a[0] * inv0 + b1a[0] * inv1;
        float v1 = bfhi(rt.x) + g1 + b0a[1] * inv0 + b1a[1] * inv1;
        float v2 = bflo(rt.y) + g2 + b0a[2] * inv0 + b1a[2] * inv1;
        float v3 = bfhi(rt.y) + g3 + b0a[3] * inv0 + b1a[3] * inv1;
        uint2 o; o.x = packbf(elu1(v0), elu1(v1)); o.y = packbf(elu1(v2), elu1(v3));
        outrow[64 + lane] = o;
    }
}

// ---------------------------------------------------------------------------
// K5: GEMM2  out = hidden + y2 @ wo.  A:[20000][288] bf16, B^T:[1024][288].
// Tile 128x128; 4 waves 2x2; wave-tile 64x64 = 4x4 MFMAs. 9 K-steps.
// hidden prefetched into registers (half at t=0, half post-K-loop);
// double-buffered global_load_lds staging.
// ---------------------------------------------------------------------------
__global__ __launch_bounds__(256, 3) void k_gemm2(
    const __bf16* __restrict__ A, const __bf16* __restrict__ Bt,
    const float* __restrict__ hidden, float* __restrict__ out)
{
    const int m0 = blockIdx.x * 128;
    const int n0 = blockIdx.y * 128;
    const int tid = threadIdx.x;
    const int lane = tid & 63, wave = tid >> 6;
    const int wm = wave >> 1, wn = wave & 1;
    const int quad = lane >> 4, l16 = lane & 15;

    __shared__ __align__(16) __bf16 As[2][128 * 32];   // 2 x 8 KB
    __shared__ __align__(16) __bf16 Bs[2][128 * 32];   // 2 x 8 KB

    // --- hidden prefetch, first half (i = 0,1): issued before anything else
    float hv[2][4][4];
    #pragma unroll
    for (int i = 0; i < 2; ++i) {
        #pragma unroll
        for (int rr = 0; rr < 4; ++rr) {
            int row = m0 + wm * 64 + i * 16 + quad * 4 + rr;
            if (row > NNODE - 1) row = NNODE - 1;
            const float* hrow = hidden + (size_t)row * DMODEL + n0 + wn * 64 + l16;
            #pragma unroll
            for (int j = 0; j < 4; ++j) hv[i][j][rr] = hrow[j * 16];
        }
    }

    floatx4 zero = {0.f, 0.f, 0.f, 0.f};
    floatx4 acc[4][4];
    #pragma unroll
    for (int i = 0; i < 4; ++i)
        #pragma unroll
        for (int j = 0; j < 4; ++j) acc[i][j] = zero;

    const int crow = lane >> 2, ccol = (lane & 3) * 8;

    auto stage = [&](int kk, int buf) {
        #pragma unroll
        for (int ii = 0; ii < 4; ++ii) {
            int c = wave + ii * 4;
            if (c < 8) {
                int grow = m0 + c * 16 + crow; if (grow > NNODE - 1) grow = NNODE - 1;
                __builtin_amdgcn_global_load_lds(
                    (gptr_t)(A + (size_t)grow * DFFP + kk + ccol),
                    (lptr_t)(As[buf] + c * 512), 16, 0, 0);
            } else {
                int nrow = n0 + (c - 8) * 16 + crow;
                __builtin_amdgcn_global_load_lds(
                    (gptr_t)(Bt + (size_t)nrow * DFFP + kk + ccol),
                    (lptr_t)(Bs[buf] + (c - 8) * 512), 16, 0, 0);
            }
        }
    };

    stage(0, 0);
    __syncthreads();
    for (int ks = 0; ks < 9; ++ks) {
        int buf = ks & 1;
        if (ks < 8) stage((ks + 1) * 32, buf ^ 1);
        bf16x8 af[4], bq[4];
        #pragma unroll
        for (int i = 0; i < 4; ++i)
            af[i] = *reinterpret_cast<const bf16x8*>(As[buf] + (wm * 64 + i * 16 + l16) * 32 + quad * 8);
        #pragma unroll
        for (int j = 0; j < 4; ++j)
            bq[j] = *reinterpret_cast<const bf16x8*>(Bs[buf] + (wn * 64 + j * 16 + l16) * 32 + quad * 8);
        #pragma unroll
        for (int i = 0; i < 4; ++i)
            #pragma unroll
            for (int j = 0; j < 4; ++j)
                acc[i][j] = __builtin_amdgcn_mfma_f32_16x16x32_bf16(af[i], bq[j], acc[i][j], 0, 0, 0);
        __syncthreads();
    }

    // --- hidden prefetch, second half (i = 2,3)
    float hw[2][4][4];
    #pragma unroll
    for (int i = 0; i < 2; ++i) {
        #pragma unroll
        for (int rr = 0; rr < 4; ++rr) {
            int row = m0 + wm * 64 + (i + 2) * 16 + quad * 4 + rr;
            if (row > NNODE - 1) row = NNODE - 1;
            const float* hrow = hidden + (size_t)row * DMODEL + n0 + wn * 64 + l16;
            #pragma unroll
            for (int j = 0; j < 4; ++j) hw[i][j][rr] = hrow[j * 16];
        }
    }

    // --- store first half while second-half loads are in flight
    #pragma unroll
    for (int i = 0; i < 2; ++i) {
        int rbase = m0 + wm * 64 + i * 16 + quad * 4;
        #pragma unroll
        for (int j = 0; j < 4; ++j) {
            int col = n0 + wn * 64 + j * 16 + l16;
            #pragma unroll
            for (int rr = 0; rr < 4; ++rr) {
                int row = rbase + rr;
                if (row < NNODE)
                    out[(size_t)row * DMODEL + col] = hv[i][j][rr] + acc[i][j][rr];
            }
        }
    }
    #pragma unroll
    for (int i = 2; i < 4; ++i) {
        int rbase = m0 + wm * 64 + i * 16 + quad * 4;
        #pragma unroll
        for (int j = 0; j < 4; ++j) {
            int col = n0 + wn * 64 + j * 16 + l16;
            #pragma unroll
            for (int rr = 0; rr < 4; ++rr) {
                int row = rbase + rr;
                if (row < NNODE)
                    out[(size_t)row * DMODEL + col] = hw[i - 2][j][rr] + acc[i][j][rr];
            }
        }
    }
}

// ---------------------------------------------------------------------------
extern "C" void kernel_launch(void* const* d_in, const int* in_sizes, int n_in,
                              void* d_out, int out_size, void* d_ws, size_t ws_size,
                              hipStream_t stream)
{
    const float* hidden   = (const float*)d_in[0];   // [20000][1024]
    const int*   ei       = (const int*)  d_in[1];   // [2][E]
    const int*   et       = (const int*)  d_in[2];   // [E]
    const float* ln_w     = (const float*)d_in[3];   // [1024]
    const float* W_rel    = (const float*)d_in[4];   // [2][1024][286]
    const float* W_root   = (const float*)d_in[5];   // [1024][286]
    const float* bias     = (const float*)d_in[6];   // [286]
    const float* wo       = (const float*)d_in[7];   // [286][1024]
    float* out = (float*)d_out;

    const int E = in_sizes[1] / 2;

    // workspace layout (bytes, 16B aligned)
    char* ws = (char*)d_ws;
    __bf16* norm_bf = (__bf16*)(ws + 0);            // 40,960,000
    __bf16* proj    = (__bf16*)(ws + 40960000);     // 34,560,000
    __bf16* y2      = (__bf16*)(ws + 75520000);     // 11,520,000
    __bf16* wroot_t = (__bf16*)(ws + 87040000);     // 589,824
    __bf16* wrel_t  = (__bf16*)(ws + 87629824);     // 1,179,648
    __bf16* wo_t    = (__bf16*)(ws + 88809472);     // 589,824
    int*    bcnt    = (int*)   (ws + 89399296);     // 80,000
    int*    boff    = (int*)   (ws + 89479296);     // 80,016
    int*    bcur    = (int*)   (ws + 89559312);     // 80,000
    int*    sorted  = (int*)   (ws + 89639312);     // 1,280,000

    hipMemsetAsync(bcnt, 0, 80000, stream);

    {
        dim3 g1((DMODEL + 31) / 32, (DFFP + 31) / 32);
        k_transpose_cast<<<g1, 256, 0, stream>>>(W_root, wroot_t, DMODEL, DFF, DMODEL, DFFP);
        k_transpose_cast<<<g1, 256, 0, stream>>>(W_rel, wrel_t, DMODEL, DFF, DMODEL, DFFP);
        k_transpose_cast<<<g1, 256, 0, stream>>>(W_rel + (size_t)DMODEL * DFF,
                                                 wrel_t + (size_t)DFFP * DMODEL,
                                                 DMODEL, DFF, DMODEL, DFFP);
        dim3 g2((DFFP + 31) / 32, (DMODEL + 31) / 32);
        k_transpose_cast<<<g2, 256, 0, stream>>>(wo, wo_t, DFF, DMODEL, DFFP, DMODEL);
    }

    k_rmsnorm<<<NNODE, 256, 0, stream>>>(hidden, ln_w, norm_bf);

    // edge sort
    k_hist<<<(E + 255) / 256, 256, 0, stream>>>(ei, bcnt, E);
    k_scan<<<1, 1024, 0, stream>>>(bcnt, boff, bcur);
    k_scatter_idx<<<(E + 255) / 256, 256, 0, stream>>>(ei, et, bcur, sorted, E);

    {
        int nmt = (NNODE + 127) / 128;   // 157
        k_gemm1<<<nmt * 3, 256, 0, stream>>>(norm_bf, wroot_t, wrel_t, proj);
    }

    k_reduce<<<NNODE / 4, 256, 0, stream>>>(boff, sorted, proj, bias, y2);

    {
        dim3 grid((NNODE + 127) / 128, DMODEL / 128);
        k_gemm2<<<grid, 256, 0, stream>>>(y2, wo_t, hidden, out);
    }
}

// Round 5
// 373.171 us; speedup vs baseline: 1.7544x; 1.0255x over previous
//
#include <hip/hip_runtime.h>
#include <hip/hip_bf16.h>

// ---------------------------------------------------------------------------
// N=20000 nodes, D_MODEL=1024, D_FF=286 (pad 288), NUM_REL=2, E=320000.
//
// Pipeline:
//   norm = rmsnorm(x) -> bf16
//   proj[z] = norm @ W_z   z in {root, rel0, rel1}   (bf16 MFMA, z-fastest)
//   counting-sort edges by dst (hist -> scan -> cursor scatter)
//   per-dst wave: gather+sum proj_rel rows (unroll 4, branchless), mean+root
//                 +bias+ELU -> y2 (bf16)
//   out = hidden + y2 @ wo  (bf16 MFMA, dbuf staging, nt residual epilogue)
// ---------------------------------------------------------------------------

typedef __bf16  bf16x8  __attribute__((ext_vector_type(8)));
typedef float   floatx4 __attribute__((ext_vector_type(4)));

#define NNODE   20000
#define DMODEL  1024
#define DFF     286
#define DFFP    288
#define NDW     144     // dwords per padded row
#define NPAIR   72      // uint2 per padded row

typedef __attribute__((address_space(1))) const void* gptr_t;
typedef __attribute__((address_space(3))) void*       lptr_t;

struct alignas(8) bf4 { __bf16 x, y, z, w; };

__device__ __forceinline__ float bflo(unsigned u) {
    union { unsigned u; float f; } c; c.u = u << 16; return c.f;
}
__device__ __forceinline__ float bfhi(unsigned u) {
    union { unsigned u; float f; } c; c.u = u & 0xffff0000u; return c.f;
}
__device__ __forceinline__ unsigned packbf(float a, float b) {
    union { __bf16 h[2]; unsigned u; } c;
    c.h[0] = (__bf16)a; c.h[1] = (__bf16)b; return c.u;
}
__device__ __forceinline__ float elu1(float v) {
    return v > 0.0f ? v : (expf(v) - 1.0f);
}

// ---------------------------------------------------------------------------
// K0: tiled transpose + cast fp32 [K][N] -> bf16 [Nout][Kout], zero-padded.
// ---------------------------------------------------------------------------
__global__ __launch_bounds__(256) void k_transpose_cast(
    const float* __restrict__ src, __bf16* __restrict__ dst,
    int K, int N, int Kout, int Nout)
{
    __shared__ float t[32][33];
    int tx = threadIdx.x & 31, ty = threadIdx.x >> 5;
    int k0 = blockIdx.x * 32, n0 = blockIdx.y * 32;
    #pragma unroll
    for (int r = 0; r < 4; ++r) {
        int k = k0 + ty + r * 8, n = n0 + tx;
        t[ty + r * 8][tx] = (k < K && n < N) ? src[(size_t)k * N + n] : 0.0f;
    }
    __syncthreads();
    #pragma unroll
    for (int r = 0; r < 4; ++r) {
        int n = n0 + ty + r * 8, k = k0 + tx;
        if (n < Nout && k < Kout) dst[(size_t)n * Kout + k] = (__bf16)t[tx][ty + r * 8];
    }
}

// ---------------------------------------------------------------------------
// K1: T5 RMSNorm, one block (256 thr) per row, float4 loads, bf16 out.
// ---------------------------------------------------------------------------
__global__ __launch_bounds__(256) void k_rmsnorm(
    const float* __restrict__ x, const float* __restrict__ w,
    __bf16* __restrict__ out)
{
    int row = blockIdx.x;
    int t = threadIdx.x;
    float4 v = reinterpret_cast<const float4*>(x + (size_t)row * DMODEL)[t];
    float ss = v.x * v.x + v.y * v.y + v.z * v.z + v.w * v.w;
    #pragma unroll
    for (int off = 32; off; off >>= 1) ss += __shfl_down(ss, off, 64);
    __shared__ float red[4];
    int lane = t & 63, wv = t >> 6;
    if (lane == 0) red[wv] = ss;
    __syncthreads();
    float tot = red[0] + red[1] + red[2] + red[3];
    float scale = rsqrtf(tot * (1.0f / (float)DMODEL) + 1e-6f);
    float4 wv4 = reinterpret_cast<const float4*>(w)[t];
    bf4 o;
    o.x = (__bf16)(v.x * scale * wv4.x);
    o.y = (__bf16)(v.y * scale * wv4.y);
    o.z = (__bf16)(v.z * scale * wv4.z);
    o.w = (__bf16)(v.w * scale * wv4.w);
    reinterpret_cast<bf4*>(out + (size_t)row * DMODEL)[t] = o;
}

// ---------------------------------------------------------------------------
// K2: GEMM1  proj[z] = norm @ B_z.   A:[20000][1024] bf16, B^T:[288][1024].
// Block = 128(M) x 288(N) for one z; 1-D grid, z fastest (A L2 reuse).
// 4 waves 2x2; wave-tile 64x144 = 4x9 MFMAs. global_load_lds staging.
// ---------------------------------------------------------------------------
__global__ __launch_bounds__(256, 2) void k_gemm1(
    const __bf16* __restrict__ A, const __bf16* __restrict__ Broot,
    const __bf16* __restrict__ Brel, __bf16* __restrict__ P)
{
    const int bid = blockIdx.x;
    const int mt = bid / 3, mz = bid - mt * 3;
    const __bf16* B = (mz == 0) ? Broot : (Brel + (size_t)(mz - 1) * DFFP * DMODEL);
    __bf16* out = P + (size_t)mz * NNODE * DFFP;

    const int m0 = mt * 128;
    const int tid = threadIdx.x;
    const int lane = tid & 63, wave = tid >> 6;
    const int wm = wave >> 1, wn = wave & 1;
    const int quad = lane >> 4, l16 = lane & 15;

    __shared__ __align__(16) __bf16 As[128 * 32];   // 8 KB
    __shared__ __align__(16) __bf16 Bs[288 * 32];   // 18 KB

    floatx4 zero = {0.f, 0.f, 0.f, 0.f};
    floatx4 acc[4][9];
    #pragma unroll
    for (int i = 0; i < 4; ++i)
        #pragma unroll
        for (int j = 0; j < 9; ++j) acc[i][j] = zero;

    const int crow = lane >> 2;          // row within 16-row chunk
    const int ccol = (lane & 3) * 8;     // bf16 col offset

    for (int k0 = 0; k0 < DMODEL; k0 += 32) {
        #pragma unroll
        for (int ii = 0; ii < 7; ++ii) {
            int c = wave + ii * 4;
            if (c < 8) {
                int row = c * 16 + crow;
                int grow = m0 + row; if (grow > NNODE - 1) grow = NNODE - 1;
                __builtin_amdgcn_global_load_lds(
                    (gptr_t)(A + (size_t)grow * DMODEL + k0 + ccol),
                    (lptr_t)(As + c * 512), 16, 0, 0);
            } else if (c < 26) {
                int nrow = (c - 8) * 16 + crow;
                __builtin_amdgcn_global_load_lds(
                    (gptr_t)(B + (size_t)nrow * DMODEL + k0 + ccol),
                    (lptr_t)(Bs + (c - 8) * 512), 16, 0, 0);
            }
        }
        __syncthreads();
        bf16x8 af[4], bq[9];
        #pragma unroll
        for (int i = 0; i < 4; ++i)
            af[i] = *reinterpret_cast<const bf16x8*>(As + (wm * 64 + i * 16 + l16) * 32 + quad * 8);
        #pragma unroll
        for (int j = 0; j < 9; ++j)
            bq[j] = *reinterpret_cast<const bf16x8*>(Bs + (wn * 144 + j * 16 + l16) * 32 + quad * 8);
        #pragma unroll
        for (int i = 0; i < 4; ++i)
            #pragma unroll
            for (int j = 0; j < 9; ++j)
                acc[i][j] = __builtin_amdgcn_mfma_f32_16x16x32_bf16(af[i], bq[j], acc[i][j], 0, 0, 0);
        __syncthreads();
    }
    #pragma unroll
    for (int i = 0; i < 4; ++i) {
        int rbase = m0 + wm * 64 + i * 16 + quad * 4;
        #pragma unroll
        for (int j = 0; j < 9; ++j) {
            int col = wn * 144 + j * 16 + l16;
            #pragma unroll
            for (int rr = 0; rr < 4; ++rr) {
                int row = rbase + rr;
                if (row < NNODE) out[(size_t)row * DFFP + col] = (__bf16)acc[i][j][rr];
            }
        }
    }
}

// ---------------------------------------------------------------------------
// K3a: histogram of edges by dst.
// ---------------------------------------------------------------------------
__global__ __launch_bounds__(256) void k_hist(
    const int* __restrict__ ei, int* __restrict__ bcnt, int E)
{
    int t = blockIdx.x * 256 + threadIdx.x;
    if (t < E) atomicAdd(&bcnt[ei[E + t]], 1);
}

// ---------------------------------------------------------------------------
// K3b: exclusive scan over 20000 bucket counts (single block, 1024 thr).
// ---------------------------------------------------------------------------
__global__ __launch_bounds__(1024) void k_scan(
    const int* __restrict__ bcnt, int* __restrict__ boff, int* __restrict__ bcur)
{
    const int CH = 20;
    __shared__ int s[1024];
    int t = threadIdx.x;
    int base = t * CH;
    int loc[CH];
    int sum = 0;
    #pragma unroll
    for (int i = 0; i < CH; ++i) {
        int idx = base + i;
        int v = (idx < NNODE) ? bcnt[idx] : 0;
        loc[i] = sum; sum += v;
    }
    s[t] = sum;
    __syncthreads();
    for (int off = 1; off < 1024; off <<= 1) {
        int v = (t >= off) ? s[t - off] : 0;
        __syncthreads();
        s[t] += v;
        __syncthreads();
    }
    int prev = (t == 0) ? 0 : s[t - 1];
    #pragma unroll
    for (int i = 0; i < CH; ++i) {
        int idx = base + i;
        if (idx < NNODE) { int o = prev + loc[i]; boff[idx] = o; bcur[idx] = o; }
    }
    if (t == 1023) boff[NNODE] = s[1023];
}

// ---------------------------------------------------------------------------
// K3c: scatter edges into sorted order; payload = src | (r<<20).
// ---------------------------------------------------------------------------
__global__ __launch_bounds__(256) void k_scatter_idx(
    const int* __restrict__ ei, const int* __restrict__ et,
    int* __restrict__ bcur, int* __restrict__ sorted, int E)
{
    int t = blockIdx.x * 256 + threadIdx.x;
    if (t >= E) return;
    int src = ei[t], dst = ei[E + t], r = et[t];
    int pos = atomicAdd(&bcur[dst], 1);
    sorted[pos] = src | (r << 20);
}

// ---------------------------------------------------------------------------
// K4: segment reduce + epilogue. One wave per dst node; uint2 gathers,
// edge loop unrolled x4 (8 gathers in flight), branchless accumulate.
// ---------------------------------------------------------------------------
__global__ __launch_bounds__(256) void k_reduce(
    const int* __restrict__ boff, const int* __restrict__ sorted,
    const __bf16* __restrict__ proj, const float* __restrict__ bias,
    __bf16* __restrict__ y2)
{
    int b = blockIdx.x * 4 + (threadIdx.x >> 6);
    int lane = threadIdx.x & 63;
    int start = boff[b], end = boff[b + 1];
    bool t8 = lane < 8;

    const uint2* base1 = reinterpret_cast<const uint2*>(proj + (size_t)NNODE * DFFP);
    const size_t relstride = (size_t)NNODE * NPAIR;

    float a0[4] = {0.f, 0.f, 0.f, 0.f}, b0a[4] = {0.f, 0.f, 0.f, 0.f};
    float a1[4] = {0.f, 0.f, 0.f, 0.f}, b1a[4] = {0.f, 0.f, 0.f, 0.f};
    float c0 = 0.f, c1 = 0.f;
    uint2 zz; zz.x = 0u; zz.y = 0u;

    int e = start;
    for (; e + 4 <= end; e += 4) {
        uint2 x[4], y[4]; float w1[4];
        #pragma unroll
        for (int u = 0; u < 4; ++u) {
            int p = sorted[e + u];
            int ri = p >> 20;
            w1[u] = (float)ri;
            const uint2* row = base1 + (size_t)(p & 0xFFFFF) * NPAIR + (ri ? relstride : 0);
            x[u] = row[lane];
            y[u] = t8 ? row[64 + lane] : zz;
        }
        #pragma unroll
        for (int u = 0; u < 4; ++u) {
            float W1 = w1[u], W0 = 1.0f - W1;
            c0 += W0; c1 += W1;
            float v0 = bflo(x[u].x), v1 = bfhi(x[u].x), v2 = bflo(x[u].y), v3 = bfhi(x[u].y);
            a0[0] += W0 * v0; a1[0] += W1 * v0;
            a0[1] += W0 * v1; a1[1] += W1 * v1;
            a0[2] += W0 * v2; a1[2] += W1 * v2;
            a0[3] += W0 * v3; a1[3] += W1 * v3;
            float u0 = bflo(y[u].x), u1 = bfhi(y[u].x), u2 = bflo(y[u].y), u3 = bfhi(y[u].y);
            b0a[0] += W0 * u0; b1a[0] += W1 * u0;
            b0a[1] += W0 * u1; b1a[1] += W1 * u1;
            b0a[2] += W0 * u2; b1a[2] += W1 * u2;
            b0a[3] += W0 * u3; b1a[3] += W1 * u3;
        }
    }
    for (; e < end; ++e) {
        int p = sorted[e];
        int ri = p >> 20;
        float W1 = (float)ri, W0 = 1.0f - W1;
        const uint2* row = base1 + (size_t)(p & 0xFFFFF) * NPAIR + (ri ? relstride : 0);
        uint2 x = row[lane];
        uint2 y = t8 ? row[64 + lane] : zz;
        c0 += W0; c1 += W1;
        float v0 = bflo(x.x), v1 = bfhi(x.x), v2 = bflo(x.y), v3 = bfhi(x.y);
        a0[0] += W0 * v0; a1[0] += W1 * v0;
        a0[1] += W0 * v1; a1[1] += W1 * v1;
        a0[2] += W0 * v2; a1[2] += W1 * v2;
        a0[3] += W0 * v3; a1[3] += W1 * v3;
        float u0 = bflo(y.x), u1 = bfhi(y.x), u2 = bflo(y.y), u3 = bfhi(y.y);
        b0a[0] += W0 * u0; b1a[0] += W1 * u0;
        b0a[1] += W0 * u1; b1a[1] += W1 * u1;
        b0a[2] += W0 * u2; b1a[2] += W1 * u2;
        b0a[3] += W0 * u3; b1a[3] += W1 * u3;
    }

    float inv0 = 1.0f / fmaxf(c0, 1.0f);
    float inv1 = 1.0f / fmaxf(c1, 1.0f);

    const uint2* rootrow = reinterpret_cast<const uint2*>(proj) + (size_t)b * NPAIR;
    uint2* outrow = reinterpret_cast<uint2*>(y2) + (size_t)b * NPAIR;

    {
        uint2 rt = rootrow[lane];
        int f = 4 * lane;                 // max 255 < 286: no guard
        float v0 = bflo(rt.x) + bias[f]     + a0[0] * inv0 + a1[0] * inv1;
        float v1 = bfhi(rt.x) + bias[f + 1] + a0[1] * inv0 + a1[1] * inv1;
        float v2 = bflo(rt.y) + bias[f + 2] + a0[2] * inv0 + a1[2] * inv1;
        float v3 = bfhi(rt.y) + bias[f + 3] + a0[3] * inv0 + a1[3] * inv1;
        uint2 o; o.x = packbf(elu1(v0), elu1(v1)); o.y = packbf(elu1(v2), elu1(v3));
        outrow[lane] = o;
    }
    if (t8) {
        uint2 rt = rootrow[64 + lane];
        int f = 256 + 4 * lane;           // 256..287: guard vs 286
        float g0 = (f     < DFF) ? bias[f]     : 0.0f;
        float g1 = (f + 1 < DFF) ? bias[f + 1] : 0.0f;
        float g2 = (f + 2 < DFF) ? bias[f + 2] : 0.0f;
        float g3 = (f + 3 < DFF) ? bias[f + 3] : 0.0f;
        float v0 = bflo(rt.x) + g0 + b0a[0] * inv0 + b1a[0] * inv1;
        float v1 = bfhi(rt.x) + g1 + b0a[1] * inv0 + b1a[1] * inv1;
        float v2 = bflo(rt.y) + g2 + b0a[2] * inv0 + b1a[2] * inv1;
        float v3 = bfhi(rt.y) + g3 + b0a[3] * inv0 + b1a[3] * inv1;
        uint2 o; o.x = packbf(elu1(v0), elu1(v1)); o.y = packbf(elu1(v2), elu1(v3));
        outrow[64 + lane] = o;
    }
}

// ---------------------------------------------------------------------------
// K5: GEMM2  out = hidden + y2 @ wo.  A:[20000][288] bf16, B^T:[1024][288].
// Tile 128x128; 4 waves 2x2; wave-tile 64x64 = 4x4 MFMAs. 9 K-steps,
// double-buffered global_load_lds staging. Epilogue: per-16-row chunk,
// 16 nontemporal hidden loads in flight, then add + nontemporal store.
// No launch_bounds occupancy cap (R4's cap at 84 VGPR caused scratch spills).
// ---------------------------------------------------------------------------
__global__ __launch_bounds__(256) void k_gemm2(
    const __bf16* __restrict__ A, const __bf16* __restrict__ Bt,
    const float* __restrict__ hidden, float* __restrict__ out)
{
    const int m0 = blockIdx.x * 128;
    const int n0 = blockIdx.y * 128;
    const int tid = threadIdx.x;
    const int lane = tid & 63, wave = tid >> 6;
    const int wm = wave >> 1, wn = wave & 1;
    const int quad = lane >> 4, l16 = lane & 15;

    __shared__ __align__(16) __bf16 As[2][128 * 32];   // 2 x 8 KB
    __shared__ __align__(16) __bf16 Bs[2][128 * 32];   // 2 x 8 KB

    floatx4 zero = {0.f, 0.f, 0.f, 0.f};
    floatx4 acc[4][4];
    #pragma unroll
    for (int i = 0; i < 4; ++i)
        #pragma unroll
        for (int j = 0; j < 4; ++j) acc[i][j] = zero;

    const int crow = lane >> 2, ccol = (lane & 3) * 8;

    auto stage = [&](int kk, int buf) {
        #pragma unroll
        for (int ii = 0; ii < 4; ++ii) {
            int c = wave + ii * 4;
            if (c < 8) {
                int grow = m0 + c * 16 + crow; if (grow > NNODE - 1) grow = NNODE - 1;
                __builtin_amdgcn_global_load_lds(
                    (gptr_t)(A + (size_t)grow * DFFP + kk + ccol),
                    (lptr_t)(As[buf] + c * 512), 16, 0, 0);
            } else {
                int nrow = n0 + (c - 8) * 16 + crow;
                __builtin_amdgcn_global_load_lds(
                    (gptr_t)(Bt + (size_t)nrow * DFFP + kk + ccol),
                    (lptr_t)(Bs[buf] + (c - 8) * 512), 16, 0, 0);
            }
        }
    };

    stage(0, 0);
    __syncthreads();
    for (int ks = 0; ks < 9; ++ks) {
        int buf = ks & 1;
        if (ks < 8) stage((ks + 1) * 32, buf ^ 1);
        bf16x8 af[4], bq[4];
        #pragma unroll
        for (int i = 0; i < 4; ++i)
            af[i] = *reinterpret_cast<const bf16x8*>(As[buf] + (wm * 64 + i * 16 + l16) * 32 + quad * 8);
        #pragma unroll
        for (int j = 0; j < 4; ++j)
            bq[j] = *reinterpret_cast<const bf16x8*>(Bs[buf] + (wn * 64 + j * 16 + l16) * 32 + quad * 8);
        #pragma unroll
        for (int i = 0; i < 4; ++i)
            #pragma unroll
            for (int j = 0; j < 4; ++j)
                acc[i][j] = __builtin_amdgcn_mfma_f32_16x16x32_bf16(af[i], bq[j], acc[i][j], 0, 0, 0);
        __syncthreads();
    }

    // epilogue: chunk of 16 rows at a time; 16 nt loads in flight, then
    // add + nt store. <=16 extra live VGPRs -> no spill.
    #pragma unroll
    for (int i = 0; i < 4; ++i) {
        int rbase = m0 + wm * 64 + i * 16 + quad * 4;
        float h[4][4];
        #pragma unroll
        for (int rr = 0; rr < 4; ++rr) {
            int row = rbase + rr; if (row > NNODE - 1) row = NNODE - 1;
            const float* hrow = hidden + (size_t)row * DMODEL + n0 + wn * 64 + l16;
            #pragma unroll
            for (int j = 0; j < 4; ++j)
                h[j][rr] = __builtin_nontemporal_load(hrow + j * 16);
        }
        #pragma unroll
        for (int j = 0; j < 4; ++j) {
            int col = n0 + wn * 64 + j * 16 + l16;
            #pragma unroll
            for (int rr = 0; rr < 4; ++rr) {
                int row = rbase + rr;
                if (row < NNODE)
                    __builtin_nontemporal_store(h[j][rr] + acc[i][j][rr],
                                                out + (size_t)row * DMODEL + col);
            }
        }
    }
}

// ---------------------------------------------------------------------------
extern "C" void kernel_launch(void* const* d_in, const int* in_sizes, int n_in,
                              void* d_out, int out_size, void* d_ws, size_t ws_size,
                              hipStream_t stream)
{
    const float* hidden   = (const float*)d_in[0];   // [20000][1024]
    const int*   ei       = (const int*)  d_in[1];   // [2][E]
    const int*   et       = (const int*)  d_in[2];   // [E]
    const float* ln_w     = (const float*)d_in[3];   // [1024]
    const float* W_rel    = (const float*)d_in[4];   // [2][1024][286]
    const float* W_root   = (const float*)d_in[5];   // [1024][286]
    const float* bias     = (const float*)d_in[6];   // [286]
    const float* wo       = (const float*)d_in[7];   // [286][1024]
    float* out = (float*)d_out;

    const int E = in_sizes[1] / 2;

    // workspace layout (bytes, 16B aligned)
    char* ws = (char*)d_ws;
    __bf16* norm_bf = (__bf16*)(ws + 0);            // 40,960,000
    __bf16* proj    = (__bf16*)(ws + 40960000);     // 34,560,000
    __bf16* y2      = (__bf16*)(ws + 75520000);     // 11,520,000
    __bf16* wroot_t = (__bf16*)(ws + 87040000);     // 589,824
    __bf16* wrel_t  = (__bf16*)(ws + 87629824);     // 1,179,648
    __bf16* wo_t    = (__bf16*)(ws + 88809472);     // 589,824
    int*    bcnt    = (int*)   (ws + 89399296);     // 80,000
    int*    boff    = (int*)   (ws + 89479296);     // 80,016
    int*    bcur    = (int*)   (ws + 89559312);     // 80,000
    int*    sorted  = (int*)   (ws + 89639312);     // 1,280,000

    hipMemsetAsync(bcnt, 0, 80000, stream);

    {
        dim3 g1((DMODEL + 31) / 32, (DFFP + 31) / 32);
        k_transpose_cast<<<g1, 256, 0, stream>>>(W_root, wroot_t, DMODEL, DFF, DMODEL, DFFP);
        k_transpose_cast<<<g1, 256, 0, stream>>>(W_rel, wrel_t, DMODEL, DFF, DMODEL, DFFP);
        k_transpose_cast<<<g1, 256, 0, stream>>>(W_rel + (size_t)DMODEL * DFF,
                                                 wrel_t + (size_t)DFFP * DMODEL,
                                                 DMODEL, DFF, DMODEL, DFFP);
        dim3 g2((DFFP + 31) / 32, (DMODEL + 31) / 32);
        k_transpose_cast<<<g2, 256, 0, stream>>>(wo, wo_t, DFF, DMODEL, DFFP, DMODEL);
    }

    k_rmsnorm<<<NNODE, 256, 0, stream>>>(hidden, ln_w, norm_bf);

    // edge sort
    k_hist<<<(E + 255) / 256, 256, 0, stream>>>(ei, bcnt, E);
    k_scan<<<1, 1024, 0, stream>>>(bcnt, boff, bcur);
    k_scatter_idx<<<(E + 255) / 256, 256, 0, stream>>>(ei, et, bcur, sorted, E);

    {
        int nmt = (NNODE + 127) / 128;   // 157
        k_gemm1<<<nmt * 3, 256, 0, stream>>>(norm_bf, wroot_t, wrel_t, proj);
    }

    k_reduce<<<NNODE / 4, 256, 0, stream>>>(boff, sorted, proj, bias, y2);

    {
        dim3 grid((NNODE + 127) / 128, DMODEL / 128);
        k_gemm2<<<grid, 256, 0, stream>>>(y2, wo_t, hidden, out);
    }
}